// Round 18
// baseline (493.715 us; speedup 1.0000x reference)
//
#include <hip/hip_runtime.h>
#include <math.h>

#define NB 32
#define NC 96
#define NT 256
#define NV 25
#define NBC 24
#define NE 24
#define CV (NC * NV)          // 2400
#define EV (NE * NV)          // 600
#define NK4 384               // 4*NC
#define NN 6400               // NT*NV
#define ACOLS 112             // padded (j,w) columns (100 -> 112)
#define APAD 40               // padded K stride in shorts (32 -> 40, conflict-free)
#define XAP 100               // Xa_lds pitch in shorts (96 c + 4 pad)
#define XAHALF (100 * XAP)    // one half-buffer: 10,000 u16 = 20,000 B

typedef __attribute__((ext_vector_type(8))) short bf16x8;
typedef __attribute__((ext_vector_type(4))) float f32x4;

__device__ __forceinline__ float hswish(float x) {
    return x * fminf(fmaxf(x + 3.f, 0.f), 6.f) * (1.f / 6.f);
}
__device__ __forceinline__ float bnval(float x, const float* p, int n, int c) {
    // p layout [4][n]: gamma, beta, rm, rv
    return (x - p[2 * n + c]) * p[c] * rsqrtf(p[3 * n + c] + 1e-5f) + p[n + c];
}
__device__ __forceinline__ unsigned short f2bf(float f) {
    unsigned u = __float_as_uint(f);
    u += 0x7fffu + ((u >> 16) & 1u);   // RNE
    return (unsigned short)(u >> 16);
}
__device__ __forceinline__ float bf2f(unsigned short us) {
    return __uint_as_float((unsigned)us << 16);
}

// ---- K1a: xm[b,c,v] = mean_t x[b,c,t,v]  AND  xsh[b,c,t][0:32] = shifted bf16 x ----
__global__ __launch_bounds__(256) void k_mean(const float* __restrict__ x,
                                              const int* __restrict__ intra,
                                              const int* __restrict__ inter,
                                              float* __restrict__ xm,
                                              unsigned short* __restrict__ xsh) {
    int bc = blockIdx.x;          // b*NC + c
    int c = bc % NC;
    int tid = threadIdx.x;        // == t
    __shared__ int colL[NV];
    if (tid < NV) {
        int s0 = (c < NC / 2) ? intra[tid] : inter[tid];
        colL[tid] = (s0 + c) % NV;
    }
    __syncthreads();
    const float* xp = x + (size_t)bc * NT * NV + (size_t)tid * NV;
    float a[NV];
#pragma unroll
    for (int v = 0; v < NV; ++v) a[v] = xp[v];
    unsigned short row[32];
#pragma unroll
    for (int v = 0; v < NV; ++v) row[v] = f2bf(a[colL[v]]);
#pragma unroll
    for (int v = NV; v < 32; ++v) row[v] = 0;
    bf16x8* dst = (bf16x8*)(xsh + ((size_t)bc * NT + tid) * 32);
#pragma unroll
    for (int s = 0; s < 4; ++s) dst[s] = ((bf16x8*)row)[s];
    __shared__ float part[4][NV];
    int lane = tid & 63, wid = tid >> 6;
#pragma unroll
    for (int v = 0; v < NV; ++v) {
        float val = a[v];
        for (int off = 32; off > 0; off >>= 1) val += __shfl_down(val, off, 64);
        if (lane == 0) part[wid][v] = val;
    }
    __syncthreads();
    if (tid < NV) {
        float s = part[0][tid] + part[1][tid] + part[2][tid] + part[3][tid];
        xm[bc * NV + tid] = s * (1.0f / NT);
    }
}

// ---- K1b: dynamic adjacency -> fused Acat^T (bf16, padded) ----
__global__ __launch_bounds__(256) void k_adyn(const float* __restrict__ xm,
                                              const float* __restrict__ Wp,
                                              const int* __restrict__ intra,
                                              const int* __restrict__ inter,
                                              const float* __restrict__ Agcn,
                                              const float* __restrict__ gate,
                                              unsigned short* __restrict__ acat) {
    int b = blockIdx.x, tid = threadIdx.x;
    __shared__ float xms[CV];
    __shared__ float embs[EV];
    __shared__ float nrm[NV];
    __shared__ float Ads[NV * NV];
    for (int i = tid; i < CV; i += 256) xms[i] = xm[b * CV + i];
    __syncthreads();
    for (int i = tid; i < EV; i += 256) {
        int e = i / NV, v = i % NV;
        int iv = intra[v], ev2 = inter[v];
        float acc = 0.f;
        for (int c = 0; c < NC; ++c) {
            int s0 = (c < NC / 2) ? iv : ev2;
            int col = (s0 + c) % NV;
            acc = fmaf(xms[c * NV + col], Wp[e * NC + c], acc);
        }
        embs[e * NV + v] = acc;
    }
    __syncthreads();
    if (tid < NV) {
        float acc = 0.f;
        for (int e = 0; e < NE; ++e) {
            float t = embs[e * NV + tid];
            acc = fmaf(t, t, acc);
        }
        nrm[tid] = sqrtf(acc) + 1e-12f;
    }
    __syncthreads();
    for (int i = tid; i < NV * NV; i += 256) {
        int v = i / NV, w = i % NV;
        float acc = 0.f;
        for (int e = 0; e < NE; ++e)
            acc = fmaf(embs[e * NV + v], embs[e * NV + w], acc);
        Ads[i] = acc / (nrm[v] * nrm[w]);
    }
    __syncthreads();
    float sg = 1.f / (1.f + expf(-gate[0]));
    for (int i = tid; i < ACOLS * APAD; i += 256) {
        int col = i / APAD, v = i % APAD;
        float val = 0.f;
        if (col < 100 && v < NV) {
            int j = col / NV, w = col % NV;
            if (j < 3) val = Agcn[(j * NV + v) * NV + w] * (1.f / 3.f);
            else val = sg * Ads[v * NV + w];
        }
        acat[(size_t)b * ACOLS * APAD + i] = f2bf(val);
    }
}

// ---- K1c: Wcat bf16 [o=96][kc=(j,c) 384] ----
__global__ __launch_bounds__(256) void k_wcat(const float* __restrict__ Wg,
                                              const float* __restrict__ Wa,
                                              unsigned short* __restrict__ wcat) {
    int i = blockIdx.x * 256 + threadIdx.x;
    if (i >= NC * NK4) return;
    int o = i / NK4, kc = i % NK4;
    int j = kc / NC, c = kc % NC;
    float v = (j < 3) ? Wg[(j * NC + o) * NC + c] : Wa[o * NC + c];
    wcat[i] = f2bf(v);
}

// ---- K1d: temporal conv A-panels wtw[2][32][96] (k = i3*24 + c2) ----
__global__ __launch_bounds__(256) void k_twp(const float* __restrict__ ta_w,
                                             const float* __restrict__ tb_w,
                                             unsigned short* __restrict__ wtw) {
    int i = blockIdx.x * 256 + threadIdx.x;
    if (i >= 2 * 32 * 96) return;
    int br = i / (32 * 96), rem = i % (32 * 96);
    int o = rem / 96, k = rem % 96;
    float v = 0.f;
    if (o < 24 && k < 72) {
        int i3 = k / 24, c2 = k % 24;
        v = (br ? tb_w : ta_w)[(o * 24 + c2) * 3 + i3];
    }
    wtw[i] = f2bf(v);
}

// ---- K2: FUSED GCN, software-pipelined: 8 jh sub-tiles (j 0..3 x half 0..1),
//      9 phases: phase p runs stage1(jh=p)->buf[p&1] || stage2(jh=p-1)<-buf[~p&1]. ----
__global__ __launch_bounds__(256) void k_gcn2(const unsigned short* __restrict__ xsh,
                                              const unsigned short* __restrict__ acat,
                                              const unsigned short* __restrict__ wcat,
                                              const float* __restrict__ gbn,
                                              unsigned short* __restrict__ x3) {
    int blk = blockIdx.x;
    int b = blk >> 5, tg = blk & 31;
    int t0 = tg * 8;
    int tid = threadIdx.x;
    __shared__ __align__(16) unsigned short Xa[2 * XAHALF];   // 40,000 B
    int lane = tid & 63, wv = tid >> 6;
    int lr = lane & 15, kg = lane >> 4;
    f32x4 acc[6][2][2];                       // [mt][half][q]
#pragma unroll
    for (int mt = 0; mt < 6; ++mt)
#pragma unroll
        for (int h = 0; h < 2; ++h)
#pragma unroll
            for (int q = 0; q < 2; ++q) acc[mt][h][q] = (f32x4){0.f, 0.f, 0.f, 0.f};

    const unsigned short* acb = acat + (size_t)b * ACOLS * APAD;
    const unsigned short* xsb = xsh + (size_t)b * NC * NT * 32;
    int cB = lr >> 2, tl = lr & 3;            // stage-1 lane mapping (4-t halves)

    for (int p = 0; p <= 8; ++p) {
        __syncthreads();
        // ---- stage 1 for jh = p (skip when p == 8) ----
        if (p < 8) {
            int j = p >> 1, h = p & 1;
            unsigned short* XaW = Xa + (p & 1) * XAHALF;
            bf16x8 af0 = *(const bf16x8*)(acb + (j * NV + lr) * APAD + kg * 8);
            bf16x8 af1 = *(const bf16x8*)(acb + (j * NV + 16 + lr) * APAD + kg * 8);
#pragma unroll
            for (int q = 0; q < 6; ++q) {
                int c = (wv * 6 + q) * 4 + cB;
                bf16x8 bf = *(const bf16x8*)(xsb + ((size_t)c * NT + t0 + h * 4 + tl) * 32 + kg * 8);
                f32x4 z = {0.f, 0.f, 0.f, 0.f};
                f32x4 c0 = __builtin_amdgcn_mfma_f32_16x16x32_bf16(af0, bf, z, 0, 0, 0);
                f32x4 c1 = __builtin_amdgcn_mfma_f32_16x16x32_bf16(af1, bf, z, 0, 0, 0);
                int base = tl * NV;
#pragma unroll
                for (int i = 0; i < 4; ++i) {
                    int w = kg * 4 + i;
                    XaW[(base + w) * XAP + c] = f2bf(c0[i]);
                }
#pragma unroll
                for (int i = 0; i < 4; ++i) {
                    int w = 16 + kg * 4 + i;
                    if (w < NV) XaW[(base + w) * XAP + c] = f2bf(c1[i]);
                }
            }
        }
        // ---- stage 2 for jh = p-1 (skip when p == 0) ----
        if (p >= 1) {
            int jh = p - 1;
            int j = jh >> 1, h = jh & 1;
            const unsigned short* XaR = Xa + (jh & 1) * XAHALF;
            const unsigned short* wj = wcat + j * NC + lr * NK4 + kg * 8;
#pragma unroll
            for (int kt = 0; kt < 3; ++kt) {
                bf16x8 af[6];
#pragma unroll
                for (int mt = 0; mt < 6; ++mt)
                    af[mt] = *(const bf16x8*)(wj + mt * 16 * NK4 + kt * 32);
#pragma unroll
                for (int q = 0; q < 2; ++q) {
                    int nf = wv * 2 + q;
                    if (nf < 7) {
                        int rowq = nf * 16 + lr;
                        bf16x8 bf;
                        if (rowq < 100) {
                            bf = *(const bf16x8*)&XaR[rowq * XAP + (kt * 4 + kg) * 8];
                        } else {
                            bf = (bf16x8){0, 0, 0, 0, 0, 0, 0, 0};
                        }
#pragma unroll
                        for (int mt = 0; mt < 6; ++mt)
                            acc[mt][h][q] = __builtin_amdgcn_mfma_f32_16x16x32_bf16(af[mt], bf, acc[mt][h][q], 0, 0, 0);
                    }
                }
            }
        }
    }
    // ---- epilogue: bn + hswish -> x3[b][o][tg*200 + h*100 + nl] ----
#pragma unroll
    for (int h = 0; h < 2; ++h)
#pragma unroll
        for (int q = 0; q < 2; ++q) {
            int nf = wv * 2 + q;
            int nl = nf * 16 + lr;
            if (nf < 7 && nl < 100) {
                size_t nbase = (size_t)b * NC * NN + tg * 200 + h * 100 + nl;
#pragma unroll
                for (int mt = 0; mt < 6; ++mt) {
#pragma unroll
                    for (int i = 0; i < 4; ++i) {
                        int o = mt * 16 + kg * 4 + i;
                        float val = hswish(bnval(acc[mt][h][q][i], gbn, NC, o));
                        x3[nbase + (size_t)o * NN] = f2bf(val);
                    }
                }
            }
        }
}

// ---- K3a: s[b,c] = mean_{t,v} x3 (bf16 in) ----
__global__ __launch_bounds__(256) void k_sred(const unsigned short* __restrict__ x3,
                                              float* __restrict__ s) {
    int bc = blockIdx.x, tid = threadIdx.x;
    const unsigned short* p = x3 + (size_t)bc * NT * NV;
    float acc = 0.f;
    for (int i = tid; i < NN / 8; i += 256) {
        bf16x8 v = *(const bf16x8*)(p + i * 8);
#pragma unroll
        for (int e = 0; e < 8; ++e) acc += bf2f((unsigned short)v[e]);
    }
    for (int off = 32; off > 0; off >>= 1) acc += __shfl_down(acc, off, 64);
    __shared__ float part[4];
    if ((tid & 63) == 0) part[tid >> 6] = acc;
    __syncthreads();
    if (tid == 0) s[bc] = (part[0] + part[1] + part[2] + part[3]) / (float)(NT * NV);
}

// ---- K3b: SE MLP -> z[b,c] ----
__global__ __launch_bounds__(128) void k_se(const float* __restrict__ s,
                                            const float* __restrict__ w1,
                                            const float* __restrict__ b1,
                                            const float* __restrict__ w2,
                                            const float* __restrict__ b2,
                                            float* __restrict__ z) {
    int b = blockIdx.x, tid = threadIdx.x;
    __shared__ float sl[NC], hl[NBC];
    if (tid < NC) sl[tid] = s[b * NC + tid];
    __syncthreads();
    if (tid < NBC) {
        float acc = b1[tid];
        for (int c = 0; c < NC; ++c) acc = fmaf(w1[tid * NC + c], sl[c], acc);
        hl[tid] = fmaxf(acc, 0.f);
    }
    __syncthreads();
    if (tid < NC) {
        float acc = b2[tid];
        for (int j = 0; j < NBC; ++j) acc = fmaf(w2[tid * NBC + j], hl[j], acc);
        z[b * NC + tid] = 1.f / (1.f + expf(-acc));
    }
}

// ---- K3c: per-b SE-folded pointwise weights Wse[b][o][c] ----
__global__ __launch_bounds__(256) void k_pww(const float* __restrict__ z,
                                             const float* __restrict__ pa_w,
                                             const float* __restrict__ pb_w,
                                             const float* __restrict__ pc_w,
                                             const float* __restrict__ pd_w,
                                             unsigned short* __restrict__ wse) {
    int i = blockIdx.x * 256 + threadIdx.x;
    if (i >= NB * NC * NC) return;
    int b = i / (NC * NC), rem = i % (NC * NC);
    int o = rem / NC, c = rem % NC;
    int br = o / NBC, lc = o % NBC;
    const float* P = (br == 0) ? pa_w : (br == 1) ? pb_w : (br == 2) ? pc_w : pd_w;
    wse[i] = f2bf(P[lc * NC + c] * z[b * NC + c]);
}

// ---- K4: MFMA pointwise. Conv channels (0..47) -> ut48[b][n][48] (transposed
//      via LDS bounce); pool/identity channels (48..95) -> u2[b][ch][n]. ----
__global__ __launch_bounds__(256) void k_pwg(const unsigned short* __restrict__ x3,
                                             const unsigned short* __restrict__ wse,
                                             const float* __restrict__ pa_bn,
                                             const float* __restrict__ pb_bn,
                                             const float* __restrict__ pc_bn,
                                             const float* __restrict__ pd_bn,
                                             unsigned short* __restrict__ ut48,
                                             unsigned short* __restrict__ u2) {
    int blk = blockIdx.x;
    int b = blk / 50;
    int n0 = (blk % 50) * 128;
    int tid = threadIdx.x;
    __shared__ __align__(16) char SMEM[33280];
    unsigned short* Wpan = (unsigned short*)SMEM;
    unsigned short* Xp = Wpan + 3 * NC * APAD;
    float* Yt = (float*)SMEM;

    int lane = tid & 63, wv = tid >> 6;
    int lr = lane & 15, kg = lane >> 4;
    f32x4 acc[6][2];
#pragma unroll
    for (int mt = 0; mt < 6; ++mt)
#pragma unroll
        for (int nn = 0; nn < 2; ++nn) acc[mt][nn] = (f32x4){0.f, 0.f, 0.f, 0.f};

    const unsigned short* wb = wse + (size_t)b * NC * NC;
    for (int i = tid; i < 3 * NC * 4; i += 256) {
        int kt = i / (NC * 4), rem = i % (NC * 4);
        int o = rem >> 2, s4 = rem & 3;
        *(bf16x8*)&Wpan[(kt * NC + o) * APAD + s4 * 8] =
            *(const bf16x8*)(wb + o * NC + kt * 32 + s4 * 8);
    }

    int kp = tid >> 4;
    int seg = tid & 15;
    const unsigned short* x3b = x3 + (size_t)b * NC * NN;

    for (int kt = 0; kt < 3; ++kt) {
        int k0 = kt * 32;
        {
            const unsigned short* src0 = x3b + (size_t)(k0 + 2 * kp) * NN + n0 + seg * 8;
            bf16x8 va = *(const bf16x8*)src0;
            bf16x8 vb = *(const bf16x8*)(src0 + NN);
            char* base = (char*)Xp;
#pragma unroll
            for (int e = 0; e < 8; ++e) {
                int n = seg * 8 + e;
                int g = (kp >> 2) ^ (n & 3) ^ ((n >> 3) & 3);
                unsigned pk = (unsigned)(unsigned short)va[e] |
                              ((unsigned)(unsigned short)vb[e] << 16);
                *(unsigned*)(base + n * 80 + g * 16 + (kp & 3) * 4) = pk;
            }
        }
        __syncthreads();
        bf16x8 afr[6];
#pragma unroll
        for (int mt = 0; mt < 6; ++mt)
            afr[mt] = *(const bf16x8*)&Wpan[(kt * NC + mt * 16 + lr) * APAD + kg * 8];
#pragma unroll
        for (int nn = 0; nn < 2; ++nn) {
            int nl = (wv * 2 + nn) * 16 + lr;
            int g = kg ^ (nl & 3) ^ ((nl >> 3) & 3);
            bf16x8 bb = *(const bf16x8*)((const char*)Xp + nl * 80 + g * 16);
#pragma unroll
            for (int mt = 0; mt < 6; ++mt)
                acc[mt][nn] = __builtin_amdgcn_mfma_f32_16x16x32_bf16(afr[mt], bb, acc[mt][nn], 0, 0, 0);
        }
        __syncthreads();
    }
#pragma unroll
    for (int mt = 0; mt < 6; ++mt)
#pragma unroll
        for (int nn = 0; nn < 2; ++nn) {
            int nl = (wv * 2 + nn) * 16 + lr;
#pragma unroll
            for (int i = 0; i < 4; ++i) {
                int o = mt * 16 + kg * 4 + i;
                int br = o / NBC, lc = o % NBC;
                const float* bnp = (br == 0) ? pa_bn : (br == 1) ? pb_bn
                                 : (br == 2) ? pc_bn : pd_bn;
                float val = bnval(acc[mt][nn][i], bnp, NBC, lc);
                if (br < 2) {
                    Yt[nl * 49 + o] = hswish(val);
                } else {
                    u2[((size_t)b * 48 + (o - 48)) * NN + n0 + nl] = f2bf(val);
                }
            }
        }
    __syncthreads();
    for (int i = tid; i < 128 * 6; i += 256) {
        int n = i / 6, og = i % 6;
        bf16x8 v;
#pragma unroll
        for (int e = 0; e < 8; ++e) v[e] = (short)f2bf(Yt[n * 49 + og * 8 + e]);
        *(bf16x8*)(ut48 + ((size_t)b * NN + n0 + n) * 48 + og * 8) = v;
    }
}

// ---- K5: MFMA temporal convs -> uc[b][oc][n] = bn(conv) (bf16, no residual) ----
__global__ __launch_bounds__(256) void k_tcnm(const unsigned short* __restrict__ ut48,
                                              const unsigned short* __restrict__ wtw,
                                              const float* __restrict__ ta_bn,
                                              const float* __restrict__ tb_bn,
                                              unsigned short* __restrict__ uc) {
    int blk = blockIdx.x;
    int b = blk / 50, n0 = (blk % 50) * 128;
    int tid = threadIdx.x;
    __shared__ __align__(16) unsigned short Ut[240][56];
    int wn = n0 - 56;
    const unsigned short* utb = ut48 + (size_t)b * NN * 48;
    for (int idx = tid; idx < 240 * 6; idx += 256) {
        int row = idx / 6, seg = idx % 6;
        int n = wn + row;
        bf16x8 val = {0, 0, 0, 0, 0, 0, 0, 0};
        if (n >= 0 && n < NN)
            val = *(const bf16x8*)(utb + (size_t)n * 48 + seg * 8);
        *(bf16x8*)&Ut[row][seg * 8] = val;
    }
    int lane = tid & 63, wave = tid >> 6;
    int lr = lane & 15, kg = lane >> 4;
    int br = wave >> 1, mh = wave & 1;
    int dn = 25 + br * 25;
    bf16x8 af[3];
#pragma unroll
    for (int kt = 0; kt < 3; ++kt)
        af[kt] = *(const bf16x8*)(wtw + (br * 32 + mh * 16 + lr) * 96 + kt * 32 + kg * 8);
    __syncthreads();

    f32x4 acc[8];
#pragma unroll
    for (int nt = 0; nt < 8; ++nt) acc[nt] = (f32x4){0.f, 0.f, 0.f, 0.f};
#pragma unroll
    for (int kt = 0; kt < 3; ++kt) {
        int g = kt * 4 + kg;
        int gg = (g > 8) ? 8 : g;
        int i3 = gg / 3;
        int c2b = (gg - i3 * 3) * 8;
        int roff = 56 + (i3 - 1) * dn;
        int colb = br * 24 + c2b;
#pragma unroll
        for (int nt = 0; nt < 8; ++nt) {
            int nrow = nt * 16 + lr + roff;
            bf16x8 bb = *(const bf16x8*)&Ut[nrow][colb];
            acc[nt] = __builtin_amdgcn_mfma_f32_16x16x32_bf16(af[kt], bb, acc[nt], 0, 0, 0);
        }
    }
    const float* bnp = br ? tb_bn : ta_bn;
    int ml = mh * 16 + kg * 4;
#pragma unroll
    for (int ii = 0; ii < 4; ++ii) {
        int ol = ml + ii;
        if (ol < 24) {
            int oc = br * 24 + ol;
#pragma unroll
            for (int nt = 0; nt < 8; ++nt) {
                int n = n0 + nt * 16 + lr;
                uc[((size_t)b * 48 + oc) * NN + n] = f2bf(bnval(acc[nt][ii], bnp, NBC, ol));
            }
        }
    }
}

// ---- K6: streaming finale: out = hswish(branch_val + x) for all 96 channels ----
__global__ __launch_bounds__(256) void k_fin(const unsigned short* __restrict__ uc,
                                             const unsigned short* __restrict__ u2,
                                             const float* __restrict__ x,
                                             float* __restrict__ out) {
    const int JV = NN / 8;
    const int NVEC = NB * NC * JV;
    for (int vid = blockIdx.x * 256 + threadIdx.x; vid < NVEC; vid += gridDim.x * 256) {
        int j = vid % JV;
        int bc = vid / JV;
        int ch = bc % NC, b = bc / NC;
        int n = j * 8;
        float val[8];
        if (ch < 48) {
            bf16x8 t = *(const bf16x8*)(uc + ((size_t)b * 48 + ch) * NN + n);
#pragma unroll
            for (int e = 0; e < 8; ++e) val[e] = bf2f((unsigned short)t[e]);
        } else if (ch < 72) {
            const unsigned short* p = u2 + ((size_t)b * 48 + (ch - 48)) * NN;
            if (j >= 4 && j <= JV - 5) {
                bf16x8 M = *(const bf16x8*)(p + n);
                bf16x8 Lm = *(const bf16x8*)(p + n - 24);
                bf16x8 Rp = *(const bf16x8*)(p + n + 24);
                float lm1 = bf2f(p[n - 25]);
                float rp1 = bf2f(p[n + 32]);
#pragma unroll
                for (int e = 0; e < 8; ++e) {
                    float vm = (e == 0) ? lm1 : bf2f((unsigned short)Lm[e - 1]);
                    float vp = (e == 7) ? rp1 : bf2f((unsigned short)Rp[e + 1]);
                    val[e] = fmaxf(fmaxf(bf2f((unsigned short)M[e]), vm), vp);
                }
            } else {
#pragma unroll
                for (int e = 0; e < 8; ++e) {
                    int ne = n + e;
                    float m = bf2f(p[ne]);
                    if (ne >= 25) m = fmaxf(m, bf2f(p[ne - 25]));
                    if (ne + 25 < NN) m = fmaxf(m, bf2f(p[ne + 25]));
                    val[e] = m;
                }
            }
        } else {
            bf16x8 t = *(const bf16x8*)(u2 + ((size_t)b * 48 + (ch - 48)) * NN + n);
#pragma unroll
            for (int e = 0; e < 8; ++e) val[e] = bf2f((unsigned short)t[e]);
        }
        const float* xp = x + (size_t)bc * NN + n;
        float* op = out + (size_t)bc * NN + n;
        f32x4 x0 = *(const f32x4*)xp;
        f32x4 x1 = *(const f32x4*)(xp + 4);
        f32x4 o0, o1;
#pragma unroll
        for (int e = 0; e < 4; ++e) o0[e] = hswish(val[e] + x0[e]);
#pragma unroll
        for (int e = 0; e < 4; ++e) o1[e] = hswish(val[e + 4] + x1[e]);
        *(f32x4*)op = o0;
        *(f32x4*)(op + 4) = o1;
    }
}

extern "C" void kernel_launch(void* const* d_in, const int* in_sizes, int n_in,
                              void* d_out, int out_size, void* d_ws, size_t ws_size,
                              hipStream_t stream) {
    const float* x = (const float*)d_in[0];
    const int* intra = (const int*)d_in[1];
    const int* inter = (const int*)d_in[2];
    const float* A_gcn = (const float*)d_in[3];
    const float* W_gcn = (const float*)d_in[4];
    const float* gcn_bn = (const float*)d_in[5];
    const float* Wp = (const float*)d_in[6];
    const float* W_adyn = (const float*)d_in[7];
    const float* gate = (const float*)d_in[8];
    const float* se_w1 = (const float*)d_in[9];
    const float* se_b1 = (const float*)d_in[10];
    const float* se_w2 = (const float*)d_in[11];
    const float* se_b2 = (const float*)d_in[12];
    const float* pa_w = (const float*)d_in[13];
    const float* pa_bn = (const float*)d_in[14];
    const float* ta_w = (const float*)d_in[15];
    const float* ta_bn = (const float*)d_in[16];
    const float* pb_w = (const float*)d_in[17];
    const float* pb_bn = (const float*)d_in[18];
    const float* tb_w = (const float*)d_in[19];
    const float* tb_bn = (const float*)d_in[20];
    const float* pc_w = (const float*)d_in[21];
    const float* pc_bn = (const float*)d_in[22];
    const float* pd_w = (const float*)d_in[23];
    const float* pd_bn = (const float*)d_in[24];
    float* out = (float*)d_out;

    // workspace layout (bytes, every slice 16B-aligned)
    char* wsb = (char*)d_ws;
    const size_t ELEMS = (size_t)NB * NC * NT * NV;        // 19,660,800
    const size_t HALF = (size_t)NB * NN * 48;              // 9,830,400
    const size_t XSH = (size_t)NB * NC * NT * 32;          // 25,165,824
    unsigned short* x3 = (unsigned short*)wsb;                       // 2*ELEMS B
    unsigned short* ut48 = x3 + ELEMS;                               // 2*HALF B ([b][n][48])
    unsigned short* u2 = ut48 + HALF;                                // 2*HALF B ([b][ch][n])
    unsigned short* uc = u2 + HALF;                                  // 2*HALF B ([b][oc][n])
    unsigned short* xsh = uc + HALF;                                 // 2*XSH B  ([b,c,t][32])
    float* xm = (float*)(xsh + XSH);                                 // 307,200 B
    float* sb = xm + NB * NC * NV;                                   // 12,288 B
    float* zb = sb + NB * NC;                                        // 12,288 B
    unsigned short* wcat = (unsigned short*)(zb + NB * NC);          // 73,728 B
    unsigned short* acat = wcat + NC * NK4;                          // 286,720 B
    unsigned short* wse = acat + NB * ACOLS * APAD;                  // 589,824 B
    unsigned short* wtw = wse + (size_t)NB * NC * NC;                // 12,288 B

    k_mean<<<NB * NC, 256, 0, stream>>>(x, intra, inter, xm, xsh);
    k_adyn<<<NB, 256, 0, stream>>>(xm, Wp, intra, inter, A_gcn, gate, acat);
    k_wcat<<<(NC * NK4 + 255) / 256, 256, 0, stream>>>(W_gcn, W_adyn, wcat);
    k_twp<<<(2 * 32 * 96 + 255) / 256, 256, 0, stream>>>(ta_w, tb_w, wtw);
    k_gcn2<<<NB * 32, 256, 0, stream>>>(xsh, acat, wcat, gcn_bn, x3);
    k_sred<<<NB * NC, 256, 0, stream>>>(x3, sb);
    k_se<<<NB, 128, 0, stream>>>(sb, se_w1, se_b1, se_w2, se_b2, zb);
    k_pww<<<(NB * NC * NC + 255) / 256, 256, 0, stream>>>(zb, pa_w, pb_w, pc_w, pd_w, wse);
    k_pwg<<<NB * 50, 256, 0, stream>>>(x3, wse, pa_bn, pb_bn, pc_bn, pd_bn, ut48, u2);
    k_tcnm<<<NB * 50, 256, 0, stream>>>(ut48, wtw, ta_bn, tb_bn, uc);
    k_fin<<<2048, 256, 0, stream>>>(uc, u2, x, out);
}

// Round 19
// 280.230 us; speedup vs baseline: 1.7618x; 1.7618x over previous
//
#include <hip/hip_runtime.h>
#include <math.h>

#define NB 32
#define NC 96
#define NT 256
#define NV 25
#define NBC 24
#define NE 24
#define CV (NC * NV)          // 2400
#define EV (NE * NV)          // 600
#define NK4 384               // 4*NC
#define NN 6400               // NT*NV
#define ACOLS 112             // padded (j,w) columns (100 -> 112)
#define APAD 40               // padded K stride in shorts (32 -> 40, conflict-free)
#define XAP 100               // Xa_lds pitch in shorts (96 c + 4 pad)
#define XAHALF (100 * XAP)    // one half-buffer: 10,000 u16 = 20,000 B

typedef __attribute__((ext_vector_type(8))) short bf16x8;
typedef __attribute__((ext_vector_type(4))) float f32x4;

__device__ __forceinline__ float hswish(float x) {
    return x * fminf(fmaxf(x + 3.f, 0.f), 6.f) * (1.f / 6.f);
}
__device__ __forceinline__ float bnval(float x, const float* p, int n, int c) {
    // p layout [4][n]: gamma, beta, rm, rv
    return (x - p[2 * n + c]) * p[c] * rsqrtf(p[3 * n + c] + 1e-5f) + p[n + c];
}
__device__ __forceinline__ unsigned short f2bf(float f) {
    unsigned u = __float_as_uint(f);
    u += 0x7fffu + ((u >> 16) & 1u);   // RNE
    return (unsigned short)(u >> 16);
}
__device__ __forceinline__ float bf2f(unsigned short us) {
    return __uint_as_float((unsigned)us << 16);
}

// ---- K1a: xm[b,c,v] = mean_t x[b,c,t,v]  AND  xsh[b,c,t][0:32] = shifted bf16 x ----
__global__ __launch_bounds__(256) void k_mean(const float* __restrict__ x,
                                              const int* __restrict__ intra,
                                              const int* __restrict__ inter,
                                              float* __restrict__ xm,
                                              unsigned short* __restrict__ xsh) {
    int bc = blockIdx.x;          // b*NC + c
    int c = bc % NC;
    int tid = threadIdx.x;        // == t
    __shared__ int colL[NV];
    if (tid < NV) {
        int s0 = (c < NC / 2) ? intra[tid] : inter[tid];
        colL[tid] = (s0 + c) % NV;
    }
    __syncthreads();
    const float* xp = x + (size_t)bc * NT * NV + (size_t)tid * NV;
    float a[NV];
#pragma unroll
    for (int v = 0; v < NV; ++v) a[v] = xp[v];
    unsigned short row[32];
#pragma unroll
    for (int v = 0; v < NV; ++v) row[v] = f2bf(a[colL[v]]);
#pragma unroll
    for (int v = NV; v < 32; ++v) row[v] = 0;
    bf16x8* dst = (bf16x8*)(xsh + ((size_t)bc * NT + tid) * 32);
#pragma unroll
    for (int s = 0; s < 4; ++s) dst[s] = ((bf16x8*)row)[s];
    __shared__ float part[4][NV];
    int lane = tid & 63, wid = tid >> 6;
#pragma unroll
    for (int v = 0; v < NV; ++v) {
        float val = a[v];
        for (int off = 32; off > 0; off >>= 1) val += __shfl_down(val, off, 64);
        if (lane == 0) part[wid][v] = val;
    }
    __syncthreads();
    if (tid < NV) {
        float s = part[0][tid] + part[1][tid] + part[2][tid] + part[3][tid];
        xm[bc * NV + tid] = s * (1.0f / NT);
    }
}

// ---- K1b: dynamic adjacency -> fused Acat^T (bf16, padded) ----
__global__ __launch_bounds__(256) void k_adyn(const float* __restrict__ xm,
                                              const float* __restrict__ Wp,
                                              const int* __restrict__ intra,
                                              const int* __restrict__ inter,
                                              const float* __restrict__ Agcn,
                                              const float* __restrict__ gate,
                                              unsigned short* __restrict__ acat) {
    int b = blockIdx.x, tid = threadIdx.x;
    __shared__ float xms[CV];
    __shared__ float embs[EV];
    __shared__ float nrm[NV];
    __shared__ float Ads[NV * NV];
    for (int i = tid; i < CV; i += 256) xms[i] = xm[b * CV + i];
    __syncthreads();
    for (int i = tid; i < EV; i += 256) {
        int e = i / NV, v = i % NV;
        int iv = intra[v], ev2 = inter[v];
        float acc = 0.f;
        for (int c = 0; c < NC; ++c) {
            int s0 = (c < NC / 2) ? iv : ev2;
            int col = (s0 + c) % NV;
            acc = fmaf(xms[c * NV + col], Wp[e * NC + c], acc);
        }
        embs[e * NV + v] = acc;
    }
    __syncthreads();
    if (tid < NV) {
        float acc = 0.f;
        for (int e = 0; e < NE; ++e) {
            float t = embs[e * NV + tid];
            acc = fmaf(t, t, acc);
        }
        nrm[tid] = sqrtf(acc) + 1e-12f;
    }
    __syncthreads();
    for (int i = tid; i < NV * NV; i += 256) {
        int v = i / NV, w = i % NV;
        float acc = 0.f;
        for (int e = 0; e < NE; ++e)
            acc = fmaf(embs[e * NV + v], embs[e * NV + w], acc);
        Ads[i] = acc / (nrm[v] * nrm[w]);
    }
    __syncthreads();
    float sg = 1.f / (1.f + expf(-gate[0]));
    for (int i = tid; i < ACOLS * APAD; i += 256) {
        int col = i / APAD, v = i % APAD;
        float val = 0.f;
        if (col < 100 && v < NV) {
            int j = col / NV, w = col % NV;
            if (j < 3) val = Agcn[(j * NV + v) * NV + w] * (1.f / 3.f);
            else val = sg * Ads[v * NV + w];
        }
        acat[(size_t)b * ACOLS * APAD + i] = f2bf(val);
    }
}

// ---- K1c: Wcat bf16 [o=96][kc=(j,c) 384] ----
__global__ __launch_bounds__(256) void k_wcat(const float* __restrict__ Wg,
                                              const float* __restrict__ Wa,
                                              unsigned short* __restrict__ wcat) {
    int i = blockIdx.x * 256 + threadIdx.x;
    if (i >= NC * NK4) return;
    int o = i / NK4, kc = i % NK4;
    int j = kc / NC, c = kc % NC;
    float v = (j < 3) ? Wg[(j * NC + o) * NC + c] : Wa[o * NC + c];
    wcat[i] = f2bf(v);
}

// ---- K1d: temporal conv A-panels wtw[2][32][96] (k = i3*24 + c2) ----
__global__ __launch_bounds__(256) void k_twp(const float* __restrict__ ta_w,
                                             const float* __restrict__ tb_w,
                                             unsigned short* __restrict__ wtw) {
    int i = blockIdx.x * 256 + threadIdx.x;
    if (i >= 2 * 32 * 96) return;
    int br = i / (32 * 96), rem = i % (32 * 96);
    int o = rem / 96, k = rem % 96;
    float v = 0.f;
    if (o < 24 && k < 72) {
        int i3 = k / 24, c2 = k % 24;
        v = (br ? tb_w : ta_w)[(o * 24 + c2) * 3 + i3];
    }
    wtw[i] = f2bf(v);
}

// ---- K2: FUSED GCN, software-pipelined. FULLY UNROLLED phase loop so every
//      acc index is compile-time (rule: runtime-indexed vec arrays spill). ----
__global__ __launch_bounds__(256) void k_gcn2(const unsigned short* __restrict__ xsh,
                                              const unsigned short* __restrict__ acat,
                                              const unsigned short* __restrict__ wcat,
                                              const float* __restrict__ gbn,
                                              unsigned short* __restrict__ x3) {
    int blk = blockIdx.x;
    int b = blk >> 5, tg = blk & 31;
    int t0 = tg * 8;
    int tid = threadIdx.x;
    __shared__ __align__(16) unsigned short Xa[2 * XAHALF];   // 40,000 B
    int lane = tid & 63, wv = tid >> 6;
    int lr = lane & 15, kg = lane >> 4;
    f32x4 acc[6][2][2];                       // [mt][half][q] — all static indices
#pragma unroll
    for (int mt = 0; mt < 6; ++mt)
#pragma unroll
        for (int h = 0; h < 2; ++h)
#pragma unroll
            for (int q = 0; q < 2; ++q) acc[mt][h][q] = (f32x4){0.f, 0.f, 0.f, 0.f};

    const unsigned short* acb = acat + (size_t)b * ACOLS * APAD;
    const unsigned short* xsb = xsh + (size_t)b * NC * NT * 32;
    int cB = lr >> 2, tl = lr & 3;            // stage-1 lane mapping (4-t halves)

#pragma unroll
    for (int p = 0; p <= 8; ++p) {
        __syncthreads();
        // ---- stage 1 for jh = p (skip when p == 8) ----
        if (p < 8) {
            const int j = p >> 1, h = p & 1;
            unsigned short* XaW = Xa + (p & 1) * XAHALF;
            bf16x8 af0 = *(const bf16x8*)(acb + (j * NV + lr) * APAD + kg * 8);
            bf16x8 af1 = *(const bf16x8*)(acb + (j * NV + 16 + lr) * APAD + kg * 8);
#pragma unroll
            for (int q = 0; q < 6; ++q) {
                int c = (wv * 6 + q) * 4 + cB;
                bf16x8 bf = *(const bf16x8*)(xsb + ((size_t)c * NT + t0 + h * 4 + tl) * 32 + kg * 8);
                f32x4 z = {0.f, 0.f, 0.f, 0.f};
                f32x4 c0 = __builtin_amdgcn_mfma_f32_16x16x32_bf16(af0, bf, z, 0, 0, 0);
                f32x4 c1 = __builtin_amdgcn_mfma_f32_16x16x32_bf16(af1, bf, z, 0, 0, 0);
                int base = tl * NV;
#pragma unroll
                for (int i = 0; i < 4; ++i) {
                    int w = kg * 4 + i;
                    XaW[(base + w) * XAP + c] = f2bf(c0[i]);
                }
#pragma unroll
                for (int i = 0; i < 4; ++i) {
                    int w = 16 + kg * 4 + i;
                    if (w < NV) XaW[(base + w) * XAP + c] = f2bf(c1[i]);
                }
            }
        }
        // ---- stage 2 for jh = p-1 (skip when p == 0) ----
        if (p >= 1) {
            const int jh = p - 1;
            const int j = jh >> 1, h = jh & 1;
            const unsigned short* XaR = Xa + (jh & 1) * XAHALF;
            const unsigned short* wj = wcat + j * NC + lr * NK4 + kg * 8;
#pragma unroll
            for (int kt = 0; kt < 3; ++kt) {
                bf16x8 af[6];
#pragma unroll
                for (int mt = 0; mt < 6; ++mt)
                    af[mt] = *(const bf16x8*)(wj + mt * 16 * NK4 + kt * 32);
#pragma unroll
                for (int q = 0; q < 2; ++q) {
                    int nf = wv * 2 + q;
                    if (nf < 7) {
                        int rowq = nf * 16 + lr;
                        bf16x8 bf;
                        if (rowq < 100) {
                            bf = *(const bf16x8*)&XaR[rowq * XAP + (kt * 4 + kg) * 8];
                        } else {
                            bf = (bf16x8){0, 0, 0, 0, 0, 0, 0, 0};
                        }
#pragma unroll
                        for (int mt = 0; mt < 6; ++mt)
                            acc[mt][h][q] = __builtin_amdgcn_mfma_f32_16x16x32_bf16(af[mt], bf, acc[mt][h][q], 0, 0, 0);
                    }
                }
            }
        }
    }
    // ---- epilogue: bn + hswish -> x3[b][o][tg*200 + h*100 + nl] ----
#pragma unroll
    for (int h = 0; h < 2; ++h)
#pragma unroll
        for (int q = 0; q < 2; ++q) {
            int nf = wv * 2 + q;
            int nl = nf * 16 + lr;
            if (nf < 7 && nl < 100) {
                size_t nbase = (size_t)b * NC * NN + tg * 200 + h * 100 + nl;
#pragma unroll
                for (int mt = 0; mt < 6; ++mt) {
#pragma unroll
                    for (int i = 0; i < 4; ++i) {
                        int o = mt * 16 + kg * 4 + i;
                        float val = hswish(bnval(acc[mt][h][q][i], gbn, NC, o));
                        x3[nbase + (size_t)o * NN] = f2bf(val);
                    }
                }
            }
        }
}

// ---- K3a: s[b,c] = mean_{t,v} x3 (bf16 in) ----
__global__ __launch_bounds__(256) void k_sred(const unsigned short* __restrict__ x3,
                                              float* __restrict__ s) {
    int bc = blockIdx.x, tid = threadIdx.x;
    const unsigned short* p = x3 + (size_t)bc * NT * NV;
    float acc = 0.f;
    for (int i = tid; i < NN / 8; i += 256) {
        bf16x8 v = *(const bf16x8*)(p + i * 8);
#pragma unroll
        for (int e = 0; e < 8; ++e) acc += bf2f((unsigned short)v[e]);
    }
    for (int off = 32; off > 0; off >>= 1) acc += __shfl_down(acc, off, 64);
    __shared__ float part[4];
    if ((tid & 63) == 0) part[tid >> 6] = acc;
    __syncthreads();
    if (tid == 0) s[bc] = (part[0] + part[1] + part[2] + part[3]) / (float)(NT * NV);
}

// ---- K3b: SE MLP -> z[b,c] ----
__global__ __launch_bounds__(128) void k_se(const float* __restrict__ s,
                                            const float* __restrict__ w1,
                                            const float* __restrict__ b1,
                                            const float* __restrict__ w2,
                                            const float* __restrict__ b2,
                                            float* __restrict__ z) {
    int b = blockIdx.x, tid = threadIdx.x;
    __shared__ float sl[NC], hl[NBC];
    if (tid < NC) sl[tid] = s[b * NC + tid];
    __syncthreads();
    if (tid < NBC) {
        float acc = b1[tid];
        for (int c = 0; c < NC; ++c) acc = fmaf(w1[tid * NC + c], sl[c], acc);
        hl[tid] = fmaxf(acc, 0.f);
    }
    __syncthreads();
    if (tid < NC) {
        float acc = b2[tid];
        for (int j = 0; j < NBC; ++j) acc = fmaf(w2[tid * NBC + j], hl[j], acc);
        z[b * NC + tid] = 1.f / (1.f + expf(-acc));
    }
}

// ---- K3c: per-b SE-folded pointwise weights Wse[b][o][c] ----
__global__ __launch_bounds__(256) void k_pww(const float* __restrict__ z,
                                             const float* __restrict__ pa_w,
                                             const float* __restrict__ pb_w,
                                             const float* __restrict__ pc_w,
                                             const float* __restrict__ pd_w,
                                             unsigned short* __restrict__ wse) {
    int i = blockIdx.x * 256 + threadIdx.x;
    if (i >= NB * NC * NC) return;
    int b = i / (NC * NC), rem = i % (NC * NC);
    int o = rem / NC, c = rem % NC;
    int br = o / NBC, lc = o % NBC;
    const float* P = (br == 0) ? pa_w : (br == 1) ? pb_w : (br == 2) ? pc_w : pd_w;
    wse[i] = f2bf(P[lc * NC + c] * z[b * NC + c]);
}

// ---- K4: MFMA pointwise. Conv channels (0..47) -> ut48[b][n][48] (transposed
//      via LDS bounce); pool/identity channels (48..95) -> u2[b][ch][n]. ----
__global__ __launch_bounds__(256) void k_pwg(const unsigned short* __restrict__ x3,
                                             const unsigned short* __restrict__ wse,
                                             const float* __restrict__ pa_bn,
                                             const float* __restrict__ pb_bn,
                                             const float* __restrict__ pc_bn,
                                             const float* __restrict__ pd_bn,
                                             unsigned short* __restrict__ ut48,
                                             unsigned short* __restrict__ u2) {
    int blk = blockIdx.x;
    int b = blk / 50;
    int n0 = (blk % 50) * 128;
    int tid = threadIdx.x;
    __shared__ __align__(16) char SMEM[33280];
    unsigned short* Wpan = (unsigned short*)SMEM;
    unsigned short* Xp = Wpan + 3 * NC * APAD;
    float* Yt = (float*)SMEM;

    int lane = tid & 63, wv = tid >> 6;
    int lr = lane & 15, kg = lane >> 4;
    f32x4 acc[6][2];
#pragma unroll
    for (int mt = 0; mt < 6; ++mt)
#pragma unroll
        for (int nn = 0; nn < 2; ++nn) acc[mt][nn] = (f32x4){0.f, 0.f, 0.f, 0.f};

    const unsigned short* wb = wse + (size_t)b * NC * NC;
    for (int i = tid; i < 3 * NC * 4; i += 256) {
        int kt = i / (NC * 4), rem = i % (NC * 4);
        int o = rem >> 2, s4 = rem & 3;
        *(bf16x8*)&Wpan[(kt * NC + o) * APAD + s4 * 8] =
            *(const bf16x8*)(wb + o * NC + kt * 32 + s4 * 8);
    }

    int kp = tid >> 4;
    int seg = tid & 15;
    const unsigned short* x3b = x3 + (size_t)b * NC * NN;

    for (int kt = 0; kt < 3; ++kt) {
        int k0 = kt * 32;
        {
            const unsigned short* src0 = x3b + (size_t)(k0 + 2 * kp) * NN + n0 + seg * 8;
            bf16x8 va = *(const bf16x8*)src0;
            bf16x8 vb = *(const bf16x8*)(src0 + NN);
            char* base = (char*)Xp;
#pragma unroll
            for (int e = 0; e < 8; ++e) {
                int n = seg * 8 + e;
                int g = (kp >> 2) ^ (n & 3) ^ ((n >> 3) & 3);
                unsigned pk = (unsigned)(unsigned short)va[e] |
                              ((unsigned)(unsigned short)vb[e] << 16);
                *(unsigned*)(base + n * 80 + g * 16 + (kp & 3) * 4) = pk;
            }
        }
        __syncthreads();
        bf16x8 afr[6];
#pragma unroll
        for (int mt = 0; mt < 6; ++mt)
            afr[mt] = *(const bf16x8*)&Wpan[(kt * NC + mt * 16 + lr) * APAD + kg * 8];
#pragma unroll
        for (int nn = 0; nn < 2; ++nn) {
            int nl = (wv * 2 + nn) * 16 + lr;
            int g = kg ^ (nl & 3) ^ ((nl >> 3) & 3);
            bf16x8 bb = *(const bf16x8*)((const char*)Xp + nl * 80 + g * 16);
#pragma unroll
            for (int mt = 0; mt < 6; ++mt)
                acc[mt][nn] = __builtin_amdgcn_mfma_f32_16x16x32_bf16(afr[mt], bb, acc[mt][nn], 0, 0, 0);
        }
        __syncthreads();
    }
#pragma unroll
    for (int mt = 0; mt < 6; ++mt)
#pragma unroll
        for (int nn = 0; nn < 2; ++nn) {
            int nl = (wv * 2 + nn) * 16 + lr;
#pragma unroll
            for (int i = 0; i < 4; ++i) {
                int o = mt * 16 + kg * 4 + i;
                int br = o / NBC, lc = o % NBC;
                const float* bnp = (br == 0) ? pa_bn : (br == 1) ? pb_bn
                                 : (br == 2) ? pc_bn : pd_bn;
                float val = bnval(acc[mt][nn][i], bnp, NBC, lc);
                if (br < 2) {
                    Yt[nl * 49 + o] = hswish(val);
                } else {
                    u2[((size_t)b * 48 + (o - 48)) * NN + n0 + nl] = f2bf(val);
                }
            }
        }
    __syncthreads();
    for (int i = tid; i < 128 * 6; i += 256) {
        int n = i / 6, og = i % 6;
        bf16x8 v;
#pragma unroll
        for (int e = 0; e < 8; ++e) v[e] = (short)f2bf(Yt[n * 49 + og * 8 + e]);
        *(bf16x8*)(ut48 + ((size_t)b * NN + n0 + n) * 48 + og * 8) = v;
    }
}

// ---- K5: MFMA temporal convs -> uc[b][oc][n] = bn(conv) (bf16, no residual) ----
__global__ __launch_bounds__(256) void k_tcnm(const unsigned short* __restrict__ ut48,
                                              const unsigned short* __restrict__ wtw,
                                              const float* __restrict__ ta_bn,
                                              const float* __restrict__ tb_bn,
                                              unsigned short* __restrict__ uc) {
    int blk = blockIdx.x;
    int b = blk / 50, n0 = (blk % 50) * 128;
    int tid = threadIdx.x;
    __shared__ __align__(16) unsigned short Ut[240][56];
    int wn = n0 - 56;
    const unsigned short* utb = ut48 + (size_t)b * NN * 48;
    for (int idx = tid; idx < 240 * 6; idx += 256) {
        int row = idx / 6, seg = idx % 6;
        int n = wn + row;
        bf16x8 val = {0, 0, 0, 0, 0, 0, 0, 0};
        if (n >= 0 && n < NN)
            val = *(const bf16x8*)(utb + (size_t)n * 48 + seg * 8);
        *(bf16x8*)&Ut[row][seg * 8] = val;
    }
    int lane = tid & 63, wave = tid >> 6;
    int lr = lane & 15, kg = lane >> 4;
    int br = wave >> 1, mh = wave & 1;
    int dn = 25 + br * 25;
    bf16x8 af[3];
#pragma unroll
    for (int kt = 0; kt < 3; ++kt)
        af[kt] = *(const bf16x8*)(wtw + (br * 32 + mh * 16 + lr) * 96 + kt * 32 + kg * 8);
    __syncthreads();

    f32x4 acc[8];
#pragma unroll
    for (int nt = 0; nt < 8; ++nt) acc[nt] = (f32x4){0.f, 0.f, 0.f, 0.f};
#pragma unroll
    for (int kt = 0; kt < 3; ++kt) {
        int g = kt * 4 + kg;
        int gg = (g > 8) ? 8 : g;
        int i3 = gg / 3;
        int c2b = (gg - i3 * 3) * 8;
        int roff = 56 + (i3 - 1) * dn;
        int colb = br * 24 + c2b;
#pragma unroll
        for (int nt = 0; nt < 8; ++nt) {
            int nrow = nt * 16 + lr + roff;
            bf16x8 bb = *(const bf16x8*)&Ut[nrow][colb];
            acc[nt] = __builtin_amdgcn_mfma_f32_16x16x32_bf16(af[kt], bb, acc[nt], 0, 0, 0);
        }
    }
    const float* bnp = br ? tb_bn : ta_bn;
    int ml = mh * 16 + kg * 4;
#pragma unroll
    for (int ii = 0; ii < 4; ++ii) {
        int ol = ml + ii;
        if (ol < 24) {
            int oc = br * 24 + ol;
#pragma unroll
            for (int nt = 0; nt < 8; ++nt) {
                int n = n0 + nt * 16 + lr;
                uc[((size_t)b * 48 + oc) * NN + n] = f2bf(bnval(acc[nt][ii], bnp, NBC, ol));
            }
        }
    }
}

// ---- K6: streaming finale: out = hswish(branch_val + x) for all 96 channels ----
__global__ __launch_bounds__(256) void k_fin(const unsigned short* __restrict__ uc,
                                             const unsigned short* __restrict__ u2,
                                             const float* __restrict__ x,
                                             float* __restrict__ out) {
    const int JV = NN / 8;
    const int NVEC = NB * NC * JV;
    for (int vid = blockIdx.x * 256 + threadIdx.x; vid < NVEC; vid += gridDim.x * 256) {
        int j = vid % JV;
        int bc = vid / JV;
        int ch = bc % NC, b = bc / NC;
        int n = j * 8;
        float val[8];
        if (ch < 48) {
            bf16x8 t = *(const bf16x8*)(uc + ((size_t)b * 48 + ch) * NN + n);
#pragma unroll
            for (int e = 0; e < 8; ++e) val[e] = bf2f((unsigned short)t[e]);
        } else if (ch < 72) {
            const unsigned short* p = u2 + ((size_t)b * 48 + (ch - 48)) * NN;
            if (j >= 4 && j <= JV - 5) {
                bf16x8 M = *(const bf16x8*)(p + n);
                bf16x8 Lm = *(const bf16x8*)(p + n - 24);
                bf16x8 Rp = *(const bf16x8*)(p + n + 24);
                float lm1 = bf2f(p[n - 25]);
                float rp1 = bf2f(p[n + 32]);
#pragma unroll
                for (int e = 0; e < 8; ++e) {
                    float vm = (e == 0) ? lm1 : bf2f((unsigned short)Lm[e - 1]);
                    float vp = (e == 7) ? rp1 : bf2f((unsigned short)Rp[e + 1]);
                    val[e] = fmaxf(fmaxf(bf2f((unsigned short)M[e]), vm), vp);
                }
            } else {
#pragma unroll
                for (int e = 0; e < 8; ++e) {
                    int ne = n + e;
                    float m = bf2f(p[ne]);
                    if (ne >= 25) m = fmaxf(m, bf2f(p[ne - 25]));
                    if (ne + 25 < NN) m = fmaxf(m, bf2f(p[ne + 25]));
                    val[e] = m;
                }
            }
        } else {
            bf16x8 t = *(const bf16x8*)(u2 + ((size_t)b * 48 + (ch - 48)) * NN + n);
#pragma unroll
            for (int e = 0; e < 8; ++e) val[e] = bf2f((unsigned short)t[e]);
        }
        const float* xp = x + (size_t)bc * NN + n;
        float* op = out + (size_t)bc * NN + n;
        f32x4 x0 = *(const f32x4*)xp;
        f32x4 x1 = *(const f32x4*)(xp + 4);
        f32x4 o0, o1;
#pragma unroll
        for (int e = 0; e < 4; ++e) o0[e] = hswish(val[e] + x0[e]);
#pragma unroll
        for (int e = 0; e < 4; ++e) o1[e] = hswish(val[e + 4] + x1[e]);
        *(f32x4*)op = o0;
        *(f32x4*)(op + 4) = o1;
    }
}

extern "C" void kernel_launch(void* const* d_in, const int* in_sizes, int n_in,
                              void* d_out, int out_size, void* d_ws, size_t ws_size,
                              hipStream_t stream) {
    const float* x = (const float*)d_in[0];
    const int* intra = (const int*)d_in[1];
    const int* inter = (const int*)d_in[2];
    const float* A_gcn = (const float*)d_in[3];
    const float* W_gcn = (const float*)d_in[4];
    const float* gcn_bn = (const float*)d_in[5];
    const float* Wp = (const float*)d_in[6];
    const float* W_adyn = (const float*)d_in[7];
    const float* gate = (const float*)d_in[8];
    const float* se_w1 = (const float*)d_in[9];
    const float* se_b1 = (const float*)d_in[10];
    const float* se_w2 = (const float*)d_in[11];
    const float* se_b2 = (const float*)d_in[12];
    const float* pa_w = (const float*)d_in[13];
    const float* pa_bn = (const float*)d_in[14];
    const float* ta_w = (const float*)d_in[15];
    const float* ta_bn = (const float*)d_in[16];
    const float* pb_w = (const float*)d_in[17];
    const float* pb_bn = (const float*)d_in[18];
    const float* tb_w = (const float*)d_in[19];
    const float* tb_bn = (const float*)d_in[20];
    const float* pc_w = (const float*)d_in[21];
    const float* pc_bn = (const float*)d_in[22];
    const float* pd_w = (const float*)d_in[23];
    const float* pd_bn = (const float*)d_in[24];
    float* out = (float*)d_out;

    // workspace layout (bytes, every slice 16B-aligned)
    char* wsb = (char*)d_ws;
    const size_t ELEMS = (size_t)NB * NC * NT * NV;        // 19,660,800
    const size_t HALF = (size_t)NB * NN * 48;              // 9,830,400
    const size_t XSH = (size_t)NB * NC * NT * 32;          // 25,165,824
    unsigned short* x3 = (unsigned short*)wsb;                       // 2*ELEMS B
    unsigned short* ut48 = x3 + ELEMS;                               // 2*HALF B ([b][n][48])
    unsigned short* u2 = ut48 + HALF;                                // 2*HALF B ([b][ch][n])
    unsigned short* uc = u2 + HALF;                                  // 2*HALF B ([b][oc][n])
    unsigned short* xsh = uc + HALF;                                 // 2*XSH B  ([b,c,t][32])
    float* xm = (float*)(xsh + XSH);                                 // 307,200 B
    float* sb = xm + NB * NC * NV;                                   // 12,288 B
    float* zb = sb + NB * NC;                                        // 12,288 B
    unsigned short* wcat = (unsigned short*)(zb + NB * NC);          // 73,728 B
    unsigned short* acat = wcat + NC * NK4;                          // 286,720 B
    unsigned short* wse = acat + NB * ACOLS * APAD;                  // 589,824 B
    unsigned short* wtw = wse + (size_t)NB * NC * NC;                // 12,288 B

    k_mean<<<NB * NC, 256, 0, stream>>>(x, intra, inter, xm, xsh);
    k_adyn<<<NB, 256, 0, stream>>>(xm, Wp, intra, inter, A_gcn, gate, acat);
    k_wcat<<<(NC * NK4 + 255) / 256, 256, 0, stream>>>(W_gcn, W_adyn, wcat);
    k_twp<<<(2 * 32 * 96 + 255) / 256, 256, 0, stream>>>(ta_w, tb_w, wtw);
    k_gcn2<<<NB * 32, 256, 0, stream>>>(xsh, acat, wcat, gcn_bn, x3);
    k_sred<<<NB * NC, 256, 0, stream>>>(x3, sb);
    k_se<<<NB, 128, 0, stream>>>(sb, se_w1, se_b1, se_w2, se_b2, zb);
    k_pww<<<(NB * NC * NC + 255) / 256, 256, 0, stream>>>(zb, pa_w, pb_w, pc_w, pd_w, wse);
    k_pwg<<<NB * 50, 256, 0, stream>>>(x3, wse, pa_bn, pb_bn, pc_bn, pd_bn, ut48, u2);
    k_tcnm<<<NB * 50, 256, 0, stream>>>(ut48, wtw, ta_bn, tb_bn, uc);
    k_fin<<<2048, 256, 0, stream>>>(uc, u2, x, out);
}

// Round 20
// 226.080 us; speedup vs baseline: 2.1838x; 1.2395x over previous
//
#include <hip/hip_runtime.h>
#include <math.h>

#define NB 32
#define NC 96
#define NT 256
#define NV 25
#define NBC 24
#define NE 24
#define CV (NC * NV)          // 2400
#define EV (NE * NV)          // 600
#define NK4 384               // 4*NC
#define NN 6400               // NT*NV
#define ACOLS 112             // padded (j,w) columns (100 -> 112)
#define APAD 40               // padded K stride in shorts (32 -> 40, conflict-free)
#define XAP 100               // Xa_lds pitch in shorts (96 c + 4 pad; 50 words -> 16 banks, free)

typedef __attribute__((ext_vector_type(8))) short bf16x8;
typedef __attribute__((ext_vector_type(4))) float f32x4;

__device__ __forceinline__ float hswish(float x) {
    return x * fminf(fmaxf(x + 3.f, 0.f), 6.f) * (1.f / 6.f);
}
__device__ __forceinline__ float bnval(float x, const float* p, int n, int c) {
    // p layout [4][n]: gamma, beta, rm, rv
    return (x - p[2 * n + c]) * p[c] * rsqrtf(p[3 * n + c] + 1e-5f) + p[n + c];
}
__device__ __forceinline__ unsigned short f2bf(float f) {
    unsigned u = __float_as_uint(f);
    u += 0x7fffu + ((u >> 16) & 1u);   // RNE
    return (unsigned short)(u >> 16);
}
__device__ __forceinline__ float bf2f(unsigned short us) {
    return __uint_as_float((unsigned)us << 16);
}

// ---- K1a: xm[b,c,v] = mean_t x[b,c,t,v]  AND  xsh[b,c,t][0:32] = shifted bf16 x ----
__global__ __launch_bounds__(256) void k_mean(const float* __restrict__ x,
                                              const int* __restrict__ intra,
                                              const int* __restrict__ inter,
                                              float* __restrict__ xm,
                                              unsigned short* __restrict__ xsh) {
    int bc = blockIdx.x;          // b*NC + c
    int c = bc % NC;
    int tid = threadIdx.x;        // == t
    __shared__ int colL[NV];
    if (tid < NV) {
        int s0 = (c < NC / 2) ? intra[tid] : inter[tid];
        colL[tid] = (s0 + c) % NV;
    }
    __syncthreads();
    const float* xp = x + (size_t)bc * NT * NV + (size_t)tid * NV;
    float a[NV];
#pragma unroll
    for (int v = 0; v < NV; ++v) a[v] = xp[v];
    unsigned short row[32];
#pragma unroll
    for (int v = 0; v < NV; ++v) row[v] = f2bf(a[colL[v]]);
#pragma unroll
    for (int v = NV; v < 32; ++v) row[v] = 0;
    bf16x8* dst = (bf16x8*)(xsh + ((size_t)bc * NT + tid) * 32);
#pragma unroll
    for (int s = 0; s < 4; ++s) dst[s] = ((bf16x8*)row)[s];
    __shared__ float part[4][NV];
    int lane = tid & 63, wid = tid >> 6;
#pragma unroll
    for (int v = 0; v < NV; ++v) {
        float val = a[v];
        for (int off = 32; off > 0; off >>= 1) val += __shfl_down(val, off, 64);
        if (lane == 0) part[wid][v] = val;
    }
    __syncthreads();
    if (tid < NV) {
        float s = part[0][tid] + part[1][tid] + part[2][tid] + part[3][tid];
        xm[bc * NV + tid] = s * (1.0f / NT);
    }
}

// ---- K1b: dynamic adjacency -> fused Acat^T (bf16, padded) ----
__global__ __launch_bounds__(256) void k_adyn(const float* __restrict__ xm,
                                              const float* __restrict__ Wp,
                                              const int* __restrict__ intra,
                                              const int* __restrict__ inter,
                                              const float* __restrict__ Agcn,
                                              const float* __restrict__ gate,
                                              unsigned short* __restrict__ acat) {
    int b = blockIdx.x, tid = threadIdx.x;
    __shared__ float xms[CV];
    __shared__ float embs[EV];
    __shared__ float nrm[NV];
    __shared__ float Ads[NV * NV];
    for (int i = tid; i < CV; i += 256) xms[i] = xm[b * CV + i];
    __syncthreads();
    for (int i = tid; i < EV; i += 256) {
        int e = i / NV, v = i % NV;
        int iv = intra[v], ev2 = inter[v];
        float acc = 0.f;
        for (int c = 0; c < NC; ++c) {
            int s0 = (c < NC / 2) ? iv : ev2;
            int col = (s0 + c) % NV;
            acc = fmaf(xms[c * NV + col], Wp[e * NC + c], acc);
        }
        embs[e * NV + v] = acc;
    }
    __syncthreads();
    if (tid < NV) {
        float acc = 0.f;
        for (int e = 0; e < NE; ++e) {
            float t = embs[e * NV + tid];
            acc = fmaf(t, t, acc);
        }
        nrm[tid] = sqrtf(acc) + 1e-12f;
    }
    __syncthreads();
    for (int i = tid; i < NV * NV; i += 256) {
        int v = i / NV, w = i % NV;
        float acc = 0.f;
        for (int e = 0; e < NE; ++e)
            acc = fmaf(embs[e * NV + v], embs[e * NV + w], acc);
        Ads[i] = acc / (nrm[v] * nrm[w]);
    }
    __syncthreads();
    float sg = 1.f / (1.f + expf(-gate[0]));
    for (int i = tid; i < ACOLS * APAD; i += 256) {
        int col = i / APAD, v = i % APAD;
        float val = 0.f;
        if (col < 100 && v < NV) {
            int j = col / NV, w = col % NV;
            if (j < 3) val = Agcn[(j * NV + v) * NV + w] * (1.f / 3.f);
            else val = sg * Ads[v * NV + w];
        }
        acat[(size_t)b * ACOLS * APAD + i] = f2bf(val);
    }
}

// ---- K1c: Wcat bf16 [o=96][kc=(j,c) 384] ----
__global__ __launch_bounds__(256) void k_wcat(const float* __restrict__ Wg,
                                              const float* __restrict__ Wa,
                                              unsigned short* __restrict__ wcat) {
    int i = blockIdx.x * 256 + threadIdx.x;
    if (i >= NC * NK4) return;
    int o = i / NK4, kc = i % NK4;
    int j = kc / NC, c = kc % NC;
    float v = (j < 3) ? Wg[(j * NC + o) * NC + c] : Wa[o * NC + c];
    wcat[i] = f2bf(v);
}

// ---- K1d: temporal conv A-panels wtw[2][32][96] (k = i3*24 + c2) ----
__global__ __launch_bounds__(256) void k_twp(const float* __restrict__ ta_w,
                                             const float* __restrict__ tb_w,
                                             unsigned short* __restrict__ wtw) {
    int i = blockIdx.x * 256 + threadIdx.x;
    if (i >= 2 * 32 * 96) return;
    int br = i / (32 * 96), rem = i % (32 * 96);
    int o = rem / 96, k = rem % 96;
    float v = 0.f;
    if (o < 24 && k < 72) {
        int i3 = k / 24, c2 = k % 24;
        v = (br ? tb_w : ta_w)[(o * 24 + c2) * 3 + i3];
    }
    wtw[i] = f2bf(v);
}

// ---- K2: FUSED GCN: x3 = hswish(bn(Σ_j W_j · (Xsh @ A_j))) — no global Xa.
//      Block = (b, tg 0..31): 8 t rows. Xa LDS exactly 40,000 B -> 4 blocks/CU. ----
__global__ __launch_bounds__(256) void k_gcn2(const unsigned short* __restrict__ xsh,
                                              const unsigned short* __restrict__ acat,
                                              const unsigned short* __restrict__ wcat,
                                              const float* __restrict__ gbn,
                                              unsigned short* __restrict__ x3) {
    int blk = blockIdx.x;
    int b = blk >> 5, tg = blk & 31;
    int t0 = tg * 8;
    int tid = threadIdx.x;
    __shared__ __align__(16) unsigned short Xa[200 * XAP];   // 40,000 B
    int lane = tid & 63, wv = tid >> 6;
    int lr = lane & 15, kg = lane >> 4;
    f32x4 acc[6][4];
#pragma unroll
    for (int mt = 0; mt < 6; ++mt)
#pragma unroll
        for (int q = 0; q < 4; ++q) acc[mt][q] = (f32x4){0.f, 0.f, 0.f, 0.f};

    const unsigned short* acb = acat + (size_t)b * ACOLS * APAD;
    const unsigned short* xsb = xsh + (size_t)b * NC * NT * 32;

    for (int j = 0; j < 4; ++j) {
        __syncthreads();                       // prev stage-2 LDS reads done
        // ---- stage 1: Xa_j[tw][c] (swapped mfma: M=w, N=(c,tl), K=v) ----
        bf16x8 af0 = *(const bf16x8*)(acb + (j * NV + lr) * APAD + kg * 8);
        bf16x8 af1 = *(const bf16x8*)(acb + (j * NV + 16 + lr) * APAD + kg * 8);
        int cB = (lr >> 3), tl = lr & 7;
#pragma unroll
        for (int q = 0; q < 12; ++q) {
            int nf = wv * 12 + q;
            int c = nf * 2 + cB;
            bf16x8 bf = *(const bf16x8*)(xsb + ((size_t)c * NT + t0 + tl) * 32 + kg * 8);
            f32x4 z = {0.f, 0.f, 0.f, 0.f};
            f32x4 c0 = __builtin_amdgcn_mfma_f32_16x16x32_bf16(af0, bf, z, 0, 0, 0);
            f32x4 c1 = __builtin_amdgcn_mfma_f32_16x16x32_bf16(af1, bf, z, 0, 0, 0);
            int base = tl * NV;
#pragma unroll
            for (int i = 0; i < 4; ++i) {
                int w = kg * 4 + i;
                Xa[(base + w) * XAP + c] = f2bf(c0[i]);
            }
#pragma unroll
            for (int i = 0; i < 4; ++i) {
                int w = 16 + kg * 4 + i;
                if (w < NV) Xa[(base + w) * XAP + c] = f2bf(c1[i]);
            }
        }
        __syncthreads();                       // Xa_j ready
        // ---- stage 2: acc += W_j × Xa_j (K = c) ----
        const unsigned short* wj = wcat + j * NC + lr * NK4 + kg * 8;
#pragma unroll
        for (int kt = 0; kt < 3; ++kt) {
            bf16x8 af[6];
#pragma unroll
            for (int mt = 0; mt < 6; ++mt)
                af[mt] = *(const bf16x8*)(wj + mt * 16 * NK4 + kt * 32);
#pragma unroll
            for (int q = 0; q < 4; ++q) {
                int nf = wv + q * 4;
                if (nf < 13) {
                    int rowq = nf * 16 + lr;
                    bf16x8 bf;
                    if (rowq < 200) {
                        bf = *(const bf16x8*)&Xa[rowq * XAP + (kt * 4 + kg) * 8];
                    } else {
                        bf = (bf16x8){0, 0, 0, 0, 0, 0, 0, 0};
                    }
#pragma unroll
                    for (int mt = 0; mt < 6; ++mt)
                        acc[mt][q] = __builtin_amdgcn_mfma_f32_16x16x32_bf16(af[mt], bf, acc[mt][q], 0, 0, 0);
                }
            }
        }
    }
    // ---- epilogue: bn + hswish -> x3[b][o][tg*200 + nl] ----
#pragma unroll
    for (int q = 0; q < 4; ++q) {
        int nf = wv + q * 4;
        int nl = nf * 16 + lr;
        if (nf < 13 && nl < 200) {
            size_t nbase = (size_t)b * NC * NN + tg * 200 + nl;
#pragma unroll
            for (int mt = 0; mt < 6; ++mt) {
#pragma unroll
                for (int i = 0; i < 4; ++i) {
                    int o = mt * 16 + kg * 4 + i;
                    float val = hswish(bnval(acc[mt][q][i], gbn, NC, o));
                    x3[nbase + (size_t)o * NN] = f2bf(val);
                }
            }
        }
    }
}

// ---- K3a: s[b,c] = mean_{t,v} x3 (bf16 in) ----
__global__ __launch_bounds__(256) void k_sred(const unsigned short* __restrict__ x3,
                                              float* __restrict__ s) {
    int bc = blockIdx.x, tid = threadIdx.x;
    const unsigned short* p = x3 + (size_t)bc * NT * NV;
    float acc = 0.f;
    for (int i = tid; i < NN / 8; i += 256) {
        bf16x8 v = *(const bf16x8*)(p + i * 8);
#pragma unroll
        for (int e = 0; e < 8; ++e) acc += bf2f((unsigned short)v[e]);
    }
    for (int off = 32; off > 0; off >>= 1) acc += __shfl_down(acc, off, 64);
    __shared__ float part[4];
    if ((tid & 63) == 0) part[tid >> 6] = acc;
    __syncthreads();
    if (tid == 0) s[bc] = (part[0] + part[1] + part[2] + part[3]) / (float)(NT * NV);
}

// ---- K3b: SE MLP -> z[b,c] ----
__global__ __launch_bounds__(128) void k_se(const float* __restrict__ s,
                                            const float* __restrict__ w1,
                                            const float* __restrict__ b1,
                                            const float* __restrict__ w2,
                                            const float* __restrict__ b2,
                                            float* __restrict__ z) {
    int b = blockIdx.x, tid = threadIdx.x;
    __shared__ float sl[NC], hl[NBC];
    if (tid < NC) sl[tid] = s[b * NC + tid];
    __syncthreads();
    if (tid < NBC) {
        float acc = b1[tid];
        for (int c = 0; c < NC; ++c) acc = fmaf(w1[tid * NC + c], sl[c], acc);
        hl[tid] = fmaxf(acc, 0.f);
    }
    __syncthreads();
    if (tid < NC) {
        float acc = b2[tid];
        for (int j = 0; j < NBC; ++j) acc = fmaf(w2[tid * NBC + j], hl[j], acc);
        z[b * NC + tid] = 1.f / (1.f + expf(-acc));
    }
}

// ---- K3c: per-b SE-folded pointwise weights Wse[b][o][c] ----
__global__ __launch_bounds__(256) void k_pww(const float* __restrict__ z,
                                             const float* __restrict__ pa_w,
                                             const float* __restrict__ pb_w,
                                             const float* __restrict__ pc_w,
                                             const float* __restrict__ pd_w,
                                             unsigned short* __restrict__ wse) {
    int i = blockIdx.x * 256 + threadIdx.x;
    if (i >= NB * NC * NC) return;
    int b = i / (NC * NC), rem = i % (NC * NC);
    int o = rem / NC, c = rem % NC;
    int br = o / NBC, lc = o % NBC;
    const float* P = (br == 0) ? pa_w : (br == 1) ? pb_w : (br == 2) ? pc_w : pd_w;
    wse[i] = f2bf(P[lc * NC + c] * z[b * NC + c]);
}

// ---- K4: MFMA pointwise. Conv channels (0..47) -> ut48[b][n][48] (transposed
//      via LDS bounce); pool/identity channels (48..95) -> u2[b][ch][n]. ----
__global__ __launch_bounds__(256) void k_pwg(const unsigned short* __restrict__ x3,
                                             const unsigned short* __restrict__ wse,
                                             const float* __restrict__ pa_bn,
                                             const float* __restrict__ pb_bn,
                                             const float* __restrict__ pc_bn,
                                             const float* __restrict__ pd_bn,
                                             unsigned short* __restrict__ ut48,
                                             unsigned short* __restrict__ u2) {
    int blk = blockIdx.x;
    int b = blk / 50;
    int n0 = (blk % 50) * 128;
    int tid = threadIdx.x;
    __shared__ __align__(16) char SMEM[33280];
    unsigned short* Wpan = (unsigned short*)SMEM;
    unsigned short* Xp = Wpan + 3 * NC * APAD;
    float* Yt = (float*)SMEM;

    int lane = tid & 63, wv = tid >> 6;
    int lr = lane & 15, kg = lane >> 4;
    f32x4 acc[6][2];
#pragma unroll
    for (int mt = 0; mt < 6; ++mt)
#pragma unroll
        for (int nn = 0; nn < 2; ++nn) acc[mt][nn] = (f32x4){0.f, 0.f, 0.f, 0.f};

    const unsigned short* wb = wse + (size_t)b * NC * NC;
    for (int i = tid; i < 3 * NC * 4; i += 256) {
        int kt = i / (NC * 4), rem = i % (NC * 4);
        int o = rem >> 2, s4 = rem & 3;
        *(bf16x8*)&Wpan[(kt * NC + o) * APAD + s4 * 8] =
            *(const bf16x8*)(wb + o * NC + kt * 32 + s4 * 8);
    }

    int kp = tid >> 4;
    int seg = tid & 15;
    const unsigned short* x3b = x3 + (size_t)b * NC * NN;

    for (int kt = 0; kt < 3; ++kt) {
        int k0 = kt * 32;
        {
            const unsigned short* src0 = x3b + (size_t)(k0 + 2 * kp) * NN + n0 + seg * 8;
            bf16x8 va = *(const bf16x8*)src0;
            bf16x8 vb = *(const bf16x8*)(src0 + NN);
            char* base = (char*)Xp;
#pragma unroll
            for (int e = 0; e < 8; ++e) {
                int n = seg * 8 + e;
                int g = (kp >> 2) ^ (n & 3) ^ ((n >> 3) & 3);
                unsigned pk = (unsigned)(unsigned short)va[e] |
                              ((unsigned)(unsigned short)vb[e] << 16);
                *(unsigned*)(base + n * 80 + g * 16 + (kp & 3) * 4) = pk;
            }
        }
        __syncthreads();
        bf16x8 afr[6];
#pragma unroll
        for (int mt = 0; mt < 6; ++mt)
            afr[mt] = *(const bf16x8*)&Wpan[(kt * NC + mt * 16 + lr) * APAD + kg * 8];
#pragma unroll
        for (int nn = 0; nn < 2; ++nn) {
            int nl = (wv * 2 + nn) * 16 + lr;
            int g = kg ^ (nl & 3) ^ ((nl >> 3) & 3);
            bf16x8 bb = *(const bf16x8*)((const char*)Xp + nl * 80 + g * 16);
#pragma unroll
            for (int mt = 0; mt < 6; ++mt)
                acc[mt][nn] = __builtin_amdgcn_mfma_f32_16x16x32_bf16(afr[mt], bb, acc[mt][nn], 0, 0, 0);
        }
        __syncthreads();
    }
#pragma unroll
    for (int mt = 0; mt < 6; ++mt)
#pragma unroll
        for (int nn = 0; nn < 2; ++nn) {
            int nl = (wv * 2 + nn) * 16 + lr;
#pragma unroll
            for (int i = 0; i < 4; ++i) {
                int o = mt * 16 + kg * 4 + i;
                int br = o / NBC, lc = o % NBC;
                const float* bnp = (br == 0) ? pa_bn : (br == 1) ? pb_bn
                                 : (br == 2) ? pc_bn : pd_bn;
                float val = bnval(acc[mt][nn][i], bnp, NBC, lc);
                if (br < 2) {
                    Yt[nl * 49 + o] = hswish(val);
                } else {
                    u2[((size_t)b * 48 + (o - 48)) * NN + n0 + nl] = f2bf(val);
                }
            }
        }
    __syncthreads();
    for (int i = tid; i < 128 * 6; i += 256) {
        int n = i / 6, og = i % 6;
        bf16x8 v;
#pragma unroll
        for (int e = 0; e < 8; ++e) v[e] = (short)f2bf(Yt[n * 49 + og * 8 + e]);
        *(bf16x8*)(ut48 + ((size_t)b * NN + n0 + n) * 48 + og * 8) = v;
    }
}

// ---- K5: MFMA temporal convs -> uc[b][oc][n] = bn(conv) (bf16, no residual) ----
__global__ __launch_bounds__(256) void k_tcnm(const unsigned short* __restrict__ ut48,
                                              const unsigned short* __restrict__ wtw,
                                              const float* __restrict__ ta_bn,
                                              const float* __restrict__ tb_bn,
                                              unsigned short* __restrict__ uc) {
    int blk = blockIdx.x;
    int b = blk / 50, n0 = (blk % 50) * 128;
    int tid = threadIdx.x;
    __shared__ __align__(16) unsigned short Ut[240][56];
    int wn = n0 - 56;
    const unsigned short* utb = ut48 + (size_t)b * NN * 48;
    for (int idx = tid; idx < 240 * 6; idx += 256) {
        int row = idx / 6, seg = idx % 6;
        int n = wn + row;
        bf16x8 val = {0, 0, 0, 0, 0, 0, 0, 0};
        if (n >= 0 && n < NN)
            val = *(const bf16x8*)(utb + (size_t)n * 48 + seg * 8);
        *(bf16x8*)&Ut[row][seg * 8] = val;
    }
    int lane = tid & 63, wave = tid >> 6;
    int lr = lane & 15, kg = lane >> 4;
    int br = wave >> 1, mh = wave & 1;
    int dn = 25 + br * 25;
    bf16x8 af[3];
#pragma unroll
    for (int kt = 0; kt < 3; ++kt)
        af[kt] = *(const bf16x8*)(wtw + (br * 32 + mh * 16 + lr) * 96 + kt * 32 + kg * 8);
    __syncthreads();

    f32x4 acc[8];
#pragma unroll
    for (int nt = 0; nt < 8; ++nt) acc[nt] = (f32x4){0.f, 0.f, 0.f, 0.f};
#pragma unroll
    for (int kt = 0; kt < 3; ++kt) {
        int g = kt * 4 + kg;
        int gg = (g > 8) ? 8 : g;
        int i3 = gg / 3;
        int c2b = (gg - i3 * 3) * 8;
        int roff = 56 + (i3 - 1) * dn;
        int colb = br * 24 + c2b;
#pragma unroll
        for (int nt = 0; nt < 8; ++nt) {
            int nrow = nt * 16 + lr + roff;
            bf16x8 bb = *(const bf16x8*)&Ut[nrow][colb];
            acc[nt] = __builtin_amdgcn_mfma_f32_16x16x32_bf16(af[kt], bb, acc[nt], 0, 0, 0);
        }
    }
    const float* bnp = br ? tb_bn : ta_bn;
    int ml = mh * 16 + kg * 4;
#pragma unroll
    for (int ii = 0; ii < 4; ++ii) {
        int ol = ml + ii;
        if (ol < 24) {
            int oc = br * 24 + ol;
#pragma unroll
            for (int nt = 0; nt < 8; ++nt) {
                int n = n0 + nt * 16 + lr;
                uc[((size_t)b * 48 + oc) * NN + n] = f2bf(bnval(acc[nt][ii], bnp, NBC, ol));
            }
        }
    }
}

// ---- K6: streaming finale: out = hswish(branch_val + x) for all 96 channels ----
__global__ __launch_bounds__(256) void k_fin(const unsigned short* __restrict__ uc,
                                             const unsigned short* __restrict__ u2,
                                             const float* __restrict__ x,
                                             float* __restrict__ out) {
    const int JV = NN / 8;
    const int NVEC = NB * NC * JV;
    for (int vid = blockIdx.x * 256 + threadIdx.x; vid < NVEC; vid += gridDim.x * 256) {
        int j = vid % JV;
        int bc = vid / JV;
        int ch = bc % NC, b = bc / NC;
        int n = j * 8;
        float val[8];
        if (ch < 48) {
            bf16x8 t = *(const bf16x8*)(uc + ((size_t)b * 48 + ch) * NN + n);
#pragma unroll
            for (int e = 0; e < 8; ++e) val[e] = bf2f((unsigned short)t[e]);
        } else if (ch < 72) {
            const unsigned short* p = u2 + ((size_t)b * 48 + (ch - 48)) * NN;
            if (j >= 4 && j <= JV - 5) {
                bf16x8 M = *(const bf16x8*)(p + n);
                bf16x8 Lm = *(const bf16x8*)(p + n - 24);
                bf16x8 Rp = *(const bf16x8*)(p + n + 24);
                float lm1 = bf2f(p[n - 25]);
                float rp1 = bf2f(p[n + 32]);
#pragma unroll
                for (int e = 0; e < 8; ++e) {
                    float vm = (e == 0) ? lm1 : bf2f((unsigned short)Lm[e - 1]);
                    float vp = (e == 7) ? rp1 : bf2f((unsigned short)Rp[e + 1]);
                    val[e] = fmaxf(fmaxf(bf2f((unsigned short)M[e]), vm), vp);
                }
            } else {
#pragma unroll
                for (int e = 0; e < 8; ++e) {
                    int ne = n + e;
                    float m = bf2f(p[ne]);
                    if (ne >= 25) m = fmaxf(m, bf2f(p[ne - 25]));
                    if (ne + 25 < NN) m = fmaxf(m, bf2f(p[ne + 25]));
                    val[e] = m;
                }
            }
        } else {
            bf16x8 t = *(const bf16x8*)(u2 + ((size_t)b * 48 + (ch - 48)) * NN + n);
#pragma unroll
            for (int e = 0; e < 8; ++e) val[e] = bf2f((unsigned short)t[e]);
        }
        const float* xp = x + (size_t)bc * NN + n;
        float* op = out + (size_t)bc * NN + n;
        f32x4 x0 = *(const f32x4*)xp;
        f32x4 x1 = *(const f32x4*)(xp + 4);
        f32x4 o0, o1;
#pragma unroll
        for (int e = 0; e < 4; ++e) o0[e] = hswish(val[e] + x0[e]);
#pragma unroll
        for (int e = 0; e < 4; ++e) o1[e] = hswish(val[e + 4] + x1[e]);
        *(f32x4*)op = o0;
        *(f32x4*)(op + 4) = o1;
    }
}

extern "C" void kernel_launch(void* const* d_in, const int* in_sizes, int n_in,
                              void* d_out, int out_size, void* d_ws, size_t ws_size,
                              hipStream_t stream) {
    const float* x = (const float*)d_in[0];
    const int* intra = (const int*)d_in[1];
    const int* inter = (const int*)d_in[2];
    const float* A_gcn = (const float*)d_in[3];
    const float* W_gcn = (const float*)d_in[4];
    const float* gcn_bn = (const float*)d_in[5];
    const float* Wp = (const float*)d_in[6];
    const float* W_adyn = (const float*)d_in[7];
    const float* gate = (const float*)d_in[8];
    const float* se_w1 = (const float*)d_in[9];
    const float* se_b1 = (const float*)d_in[10];
    const float* se_w2 = (const float*)d_in[11];
    const float* se_b2 = (const float*)d_in[12];
    const float* pa_w = (const float*)d_in[13];
    const float* pa_bn = (const float*)d_in[14];
    const float* ta_w = (const float*)d_in[15];
    const float* ta_bn = (const float*)d_in[16];
    const float* pb_w = (const float*)d_in[17];
    const float* pb_bn = (const float*)d_in[18];
    const float* tb_w = (const float*)d_in[19];
    const float* tb_bn = (const float*)d_in[20];
    const float* pc_w = (const float*)d_in[21];
    const float* pc_bn = (const float*)d_in[22];
    const float* pd_w = (const float*)d_in[23];
    const float* pd_bn = (const float*)d_in[24];
    float* out = (float*)d_out;

    // workspace layout (bytes, every slice 16B-aligned)
    char* wsb = (char*)d_ws;
    const size_t ELEMS = (size_t)NB * NC * NT * NV;        // 19,660,800
    const size_t HALF = (size_t)NB * NN * 48;              // 9,830,400
    const size_t XSH = (size_t)NB * NC * NT * 32;          // 25,165,824
    unsigned short* x3 = (unsigned short*)wsb;                       // 2*ELEMS B
    unsigned short* ut48 = x3 + ELEMS;                               // 2*HALF B ([b][n][48])
    unsigned short* u2 = ut48 + HALF;                                // 2*HALF B ([b][ch][n])
    unsigned short* uc = u2 + HALF;                                  // 2*HALF B ([b][oc][n])
    unsigned short* xsh = uc + HALF;                                 // 2*XSH B  ([b,c,t][32])
    float* xm = (float*)(xsh + XSH);                                 // 307,200 B
    float* sb = xm + NB * NC * NV;                                   // 12,288 B
    float* zb = sb + NB * NC;                                        // 12,288 B
    unsigned short* wcat = (unsigned short*)(zb + NB * NC);          // 73,728 B
    unsigned short* acat = wcat + NC * NK4;                          // 286,720 B
    unsigned short* wse = acat + NB * ACOLS * APAD;                  // 589,824 B
    unsigned short* wtw = wse + (size_t)NB * NC * NC;                // 12,288 B

    k_mean<<<NB * NC, 256, 0, stream>>>(x, intra, inter, xm, xsh);
    k_adyn<<<NB, 256, 0, stream>>>(xm, Wp, intra, inter, A_gcn, gate, acat);
    k_wcat<<<(NC * NK4 + 255) / 256, 256, 0, stream>>>(W_gcn, W_adyn, wcat);
    k_twp<<<(2 * 32 * 96 + 255) / 256, 256, 0, stream>>>(ta_w, tb_w, wtw);
    k_gcn2<<<NB * 32, 256, 0, stream>>>(xsh, acat, wcat, gcn_bn, x3);
    k_sred<<<NB * NC, 256, 0, stream>>>(x3, sb);
    k_se<<<NB, 128, 0, stream>>>(sb, se_w1, se_b1, se_w2, se_b2, zb);
    k_pww<<<(NB * NC * NC + 255) / 256, 256, 0, stream>>>(zb, pa_w, pb_w, pc_w, pd_w, wse);
    k_pwg<<<NB * 50, 256, 0, stream>>>(x3, wse, pa_bn, pb_bn, pc_bn, pd_bn, ut48, u2);
    k_tcnm<<<NB * 50, 256, 0, stream>>>(ut48, wtw, ta_bn, tb_bn, uc);
    k_fin<<<2048, 256, 0, stream>>>(uc, u2, x, out);
}

// Round 21
// 220.975 us; speedup vs baseline: 2.2343x; 1.0231x over previous
//
#include <hip/hip_runtime.h>
#include <math.h>

#define NB 32
#define NC 96
#define NT 256
#define NV 25
#define NBC 24
#define NE 24
#define CV (NC * NV)          // 2400
#define EV (NE * NV)          // 600
#define NK4 384               // 4*NC
#define NN 6400               // NT*NV
#define ACOLS 112             // padded (j,w) columns (100 -> 112)
#define APAD 40               // padded K stride in shorts (32 -> 40, conflict-free)
#define XAP 100               // Xa_lds pitch in shorts (96 c + 4 pad; 50 words -> 16 banks, free)

typedef __attribute__((ext_vector_type(8))) short bf16x8;
typedef __attribute__((ext_vector_type(4))) float f32x4;
typedef __attribute__((ext_vector_type(2))) unsigned int u32x2;

__device__ __forceinline__ float hswish(float x) {
    return x * fminf(fmaxf(x + 3.f, 0.f), 6.f) * (1.f / 6.f);
}
__device__ __forceinline__ float bnval(float x, const float* p, int n, int c) {
    // p layout [4][n]: gamma, beta, rm, rv
    return (x - p[2 * n + c]) * p[c] * rsqrtf(p[3 * n + c] + 1e-5f) + p[n + c];
}
__device__ __forceinline__ unsigned short f2bf(float f) {
    unsigned u = __float_as_uint(f);
    u += 0x7fffu + ((u >> 16) & 1u);   // RNE
    return (unsigned short)(u >> 16);
}
__device__ __forceinline__ float bf2f(unsigned short us) {
    return __uint_as_float((unsigned)us << 16);
}

// ---- K1a: xm[b,c,v] = mean_t x[b,c,t,v]  AND  xsh[b,c,t][0:32] = shifted bf16 x ----
__global__ __launch_bounds__(256) void k_mean(const float* __restrict__ x,
                                              const int* __restrict__ intra,
                                              const int* __restrict__ inter,
                                              float* __restrict__ xm,
                                              unsigned short* __restrict__ xsh) {
    int bc = blockIdx.x;          // b*NC + c
    int c = bc % NC;
    int tid = threadIdx.x;        // == t
    __shared__ int colL[NV];
    if (tid < NV) {
        int s0 = (c < NC / 2) ? intra[tid] : inter[tid];
        colL[tid] = (s0 + c) % NV;
    }
    __syncthreads();
    const float* xp = x + (size_t)bc * NT * NV + (size_t)tid * NV;
    float a[NV];
#pragma unroll
    for (int v = 0; v < NV; ++v) a[v] = xp[v];
    unsigned short row[32];
#pragma unroll
    for (int v = 0; v < NV; ++v) row[v] = f2bf(a[colL[v]]);
#pragma unroll
    for (int v = NV; v < 32; ++v) row[v] = 0;
    bf16x8* dst = (bf16x8*)(xsh + ((size_t)bc * NT + tid) * 32);
#pragma unroll
    for (int s = 0; s < 4; ++s) dst[s] = ((bf16x8*)row)[s];
    __shared__ float part[4][NV];
    int lane = tid & 63, wid = tid >> 6;
#pragma unroll
    for (int v = 0; v < NV; ++v) {
        float val = a[v];
        for (int off = 32; off > 0; off >>= 1) val += __shfl_down(val, off, 64);
        if (lane == 0) part[wid][v] = val;
    }
    __syncthreads();
    if (tid < NV) {
        float s = part[0][tid] + part[1][tid] + part[2][tid] + part[3][tid];
        xm[bc * NV + tid] = s * (1.0f / NT);
    }
}

// ---- K1b: dynamic adjacency -> fused Acat^T (bf16, padded) ----
__global__ __launch_bounds__(256) void k_adyn(const float* __restrict__ xm,
                                              const float* __restrict__ Wp,
                                              const int* __restrict__ intra,
                                              const int* __restrict__ inter,
                                              const float* __restrict__ Agcn,
                                              const float* __restrict__ gate,
                                              unsigned short* __restrict__ acat) {
    int b = blockIdx.x, tid = threadIdx.x;
    __shared__ float xms[CV];
    __shared__ float embs[EV];
    __shared__ float nrm[NV];
    __shared__ float Ads[NV * NV];
    for (int i = tid; i < CV; i += 256) xms[i] = xm[b * CV + i];
    __syncthreads();
    for (int i = tid; i < EV; i += 256) {
        int e = i / NV, v = i % NV;
        int iv = intra[v], ev2 = inter[v];
        float acc = 0.f;
        for (int c = 0; c < NC; ++c) {
            int s0 = (c < NC / 2) ? iv : ev2;
            int col = (s0 + c) % NV;
            acc = fmaf(xms[c * NV + col], Wp[e * NC + c], acc);
        }
        embs[e * NV + v] = acc;
    }
    __syncthreads();
    if (tid < NV) {
        float acc = 0.f;
        for (int e = 0; e < NE; ++e) {
            float t = embs[e * NV + tid];
            acc = fmaf(t, t, acc);
        }
        nrm[tid] = sqrtf(acc) + 1e-12f;
    }
    __syncthreads();
    for (int i = tid; i < NV * NV; i += 256) {
        int v = i / NV, w = i % NV;
        float acc = 0.f;
        for (int e = 0; e < NE; ++e)
            acc = fmaf(embs[e * NV + v], embs[e * NV + w], acc);
        Ads[i] = acc / (nrm[v] * nrm[w]);
    }
    __syncthreads();
    float sg = 1.f / (1.f + expf(-gate[0]));
    for (int i = tid; i < ACOLS * APAD; i += 256) {
        int col = i / APAD, v = i % APAD;
        float val = 0.f;
        if (col < 100 && v < NV) {
            int j = col / NV, w = col % NV;
            if (j < 3) val = Agcn[(j * NV + v) * NV + w] * (1.f / 3.f);
            else val = sg * Ads[v * NV + w];
        }
        acat[(size_t)b * ACOLS * APAD + i] = f2bf(val);
    }
}

// ---- K1c: Wcat bf16 [o=96][kc=(j,c) 384] ----
__global__ __launch_bounds__(256) void k_wcat(const float* __restrict__ Wg,
                                              const float* __restrict__ Wa,
                                              unsigned short* __restrict__ wcat) {
    int i = blockIdx.x * 256 + threadIdx.x;
    if (i >= NC * NK4) return;
    int o = i / NK4, kc = i % NK4;
    int j = kc / NC, c = kc % NC;
    float v = (j < 3) ? Wg[(j * NC + o) * NC + c] : Wa[o * NC + c];
    wcat[i] = f2bf(v);
}

// ---- K1d: temporal conv A-panels wtw[2][32][96] (k = i3*24 + c2) ----
__global__ __launch_bounds__(256) void k_twp(const float* __restrict__ ta_w,
                                             const float* __restrict__ tb_w,
                                             unsigned short* __restrict__ wtw) {
    int i = blockIdx.x * 256 + threadIdx.x;
    if (i >= 2 * 32 * 96) return;
    int br = i / (32 * 96), rem = i % (32 * 96);
    int o = rem / 96, k = rem % 96;
    float v = 0.f;
    if (o < 24 && k < 72) {
        int i3 = k / 24, c2 = k % 24;
        v = (br ? tb_w : ta_w)[(o * 24 + c2) * 3 + i3];
    }
    wtw[i] = f2bf(v);
}

// ---- K2: FUSED GCN: x3 = hswish(bn(Σ_j W_j · (Xsh @ A_j))) — no global Xa.
//      Block = (b, tg 0..31): 8 t rows. Stage-1 uses A=xsh (M = 4t x 4c) so the
//      C-fragment's 4 values are CONTIGUOUS c -> one uint2 LDS write (was 8 b16). ----
__global__ __launch_bounds__(256) void k_gcn2(const unsigned short* __restrict__ xsh,
                                              const unsigned short* __restrict__ acat,
                                              const unsigned short* __restrict__ wcat,
                                              const float* __restrict__ gbn,
                                              unsigned short* __restrict__ x3) {
    int blk = blockIdx.x;
    int b = blk >> 5, tg = blk & 31;
    int t0 = tg * 8;
    int tid = threadIdx.x;
    __shared__ __align__(16) unsigned short Xa[200 * XAP];   // 40,000 B
    int lane = tid & 63, wv = tid >> 6;
    int lr = lane & 15, kg = lane >> 4;
    f32x4 acc[6][4];
#pragma unroll
    for (int mt = 0; mt < 6; ++mt)
#pragma unroll
        for (int q = 0; q < 4; ++q) acc[mt][q] = (f32x4){0.f, 0.f, 0.f, 0.f};

    const unsigned short* acb = acat + (size_t)b * ACOLS * APAD;
    const unsigned short* xsb = xsh + (size_t)b * NC * NT * 32;
    int cA = lr & 3, tA = lr >> 2;            // stage-1 A-frag row = t_local*4 + c_local

    for (int j = 0; j < 4; ++j) {
        __syncthreads();                       // prev stage-2 LDS reads done
        // ---- stage 1: Xa_j[t*25+w][c] via mfma(A=xsh, B=acat) ----
        // B-frags: lane&15 -> w column, kg*8 contiguous v
        bf16x8 bw0 = *(const bf16x8*)(acb + (j * NV + lr) * APAD + kg * 8);
        bf16x8 bw1 = *(const bf16x8*)(acb + (j * NV + 16 + lr) * APAD + kg * 8);
#pragma unroll
        for (int tq = 0; tq < 2; ++tq) {
#pragma unroll
            for (int qc = 0; qc < 6; ++qc) {
                int cg = wv * 6 + qc;
                int c = cg * 4 + cA;
                int t = t0 + tq * 4 + tA;
                bf16x8 afx = *(const bf16x8*)(xsb + ((size_t)c * NT + t) * 32 + kg * 8);
                f32x4 z = {0.f, 0.f, 0.f, 0.f};
                f32x4 c0 = __builtin_amdgcn_mfma_f32_16x16x32_bf16(afx, bw0, z, 0, 0, 0);
                f32x4 c1 = __builtin_amdgcn_mfma_f32_16x16x32_bf16(afx, bw1, z, 0, 0, 0);
                // thread output: t_rel = tq*4+kg, w = lr (+16), c = cg*4 + i (contiguous)
                int rowb = (tq * 4 + kg) * NV;
                u32x2 pk0;
                pk0.x = (unsigned)f2bf(c0[0]) | ((unsigned)f2bf(c0[1]) << 16);
                pk0.y = (unsigned)f2bf(c0[2]) | ((unsigned)f2bf(c0[3]) << 16);
                *(u32x2*)&Xa[(rowb + lr) * XAP + cg * 4] = pk0;
                if (lr < 9) {
                    u32x2 pk1;
                    pk1.x = (unsigned)f2bf(c1[0]) | ((unsigned)f2bf(c1[1]) << 16);
                    pk1.y = (unsigned)f2bf(c1[2]) | ((unsigned)f2bf(c1[3]) << 16);
                    *(u32x2*)&Xa[(rowb + 16 + lr) * XAP + cg * 4] = pk1;
                }
            }
        }
        __syncthreads();                       // Xa_j ready
        // ---- stage 2: acc += W_j × Xa_j (K = c) ----
        const unsigned short* wj = wcat + j * NC + lr * NK4 + kg * 8;
#pragma unroll
        for (int kt = 0; kt < 3; ++kt) {
            bf16x8 af[6];
#pragma unroll
            for (int mt = 0; mt < 6; ++mt)
                af[mt] = *(const bf16x8*)(wj + mt * 16 * NK4 + kt * 32);
#pragma unroll
            for (int q = 0; q < 4; ++q) {
                int nf = wv + q * 4;
                if (nf < 13) {
                    int rowq = nf * 16 + lr;
                    bf16x8 bf;
                    if (rowq < 200) {
                        bf = *(const bf16x8*)&Xa[rowq * XAP + (kt * 4 + kg) * 8];
                    } else {
                        bf = (bf16x8){0, 0, 0, 0, 0, 0, 0, 0};
                    }
#pragma unroll
                    for (int mt = 0; mt < 6; ++mt)
                        acc[mt][q] = __builtin_amdgcn_mfma_f32_16x16x32_bf16(af[mt], bf, acc[mt][q], 0, 0, 0);
                }
            }
        }
    }
    // ---- epilogue: bn + hswish -> x3[b][o][tg*200 + nl] ----
#pragma unroll
    for (int q = 0; q < 4; ++q) {
        int nf = wv + q * 4;
        int nl = nf * 16 + lr;
        if (nf < 13 && nl < 200) {
            size_t nbase = (size_t)b * NC * NN + tg * 200 + nl;
#pragma unroll
            for (int mt = 0; mt < 6; ++mt) {
#pragma unroll
                for (int i = 0; i < 4; ++i) {
                    int o = mt * 16 + kg * 4 + i;
                    float val = hswish(bnval(acc[mt][q][i], gbn, NC, o));
                    x3[nbase + (size_t)o * NN] = f2bf(val);
                }
            }
        }
    }
}

// ---- K3a: s[b,c] = mean_{t,v} x3 (bf16 in) ----
__global__ __launch_bounds__(256) void k_sred(const unsigned short* __restrict__ x3,
                                              float* __restrict__ s) {
    int bc = blockIdx.x, tid = threadIdx.x;
    const unsigned short* p = x3 + (size_t)bc * NT * NV;
    float acc = 0.f;
    for (int i = tid; i < NN / 8; i += 256) {
        bf16x8 v = *(const bf16x8*)(p + i * 8);
#pragma unroll
        for (int e = 0; e < 8; ++e) acc += bf2f((unsigned short)v[e]);
    }
    for (int off = 32; off > 0; off >>= 1) acc += __shfl_down(acc, off, 64);
    __shared__ float part[4];
    if ((tid & 63) == 0) part[tid >> 6] = acc;
    __syncthreads();
    if (tid == 0) s[bc] = (part[0] + part[1] + part[2] + part[3]) / (float)(NT * NV);
}

// ---- K3b: SE MLP -> z[b,c] ----
__global__ __launch_bounds__(128) void k_se(const float* __restrict__ s,
                                            const float* __restrict__ w1,
                                            const float* __restrict__ b1,
                                            const float* __restrict__ w2,
                                            const float* __restrict__ b2,
                                            float* __restrict__ z) {
    int b = blockIdx.x, tid = threadIdx.x;
    __shared__ float sl[NC], hl[NBC];
    if (tid < NC) sl[tid] = s[b * NC + tid];
    __syncthreads();
    if (tid < NBC) {
        float acc = b1[tid];
        for (int c = 0; c < NC; ++c) acc = fmaf(w1[tid * NC + c], sl[c], acc);
        hl[tid] = fmaxf(acc, 0.f);
    }
    __syncthreads();
    if (tid < NC) {
        float acc = b2[tid];
        for (int j = 0; j < NBC; ++j) acc = fmaf(w2[tid * NBC + j], hl[j], acc);
        z[b * NC + tid] = 1.f / (1.f + expf(-acc));
    }
}

// ---- K3c: per-b SE-folded pointwise weights Wse[b][o][c] ----
__global__ __launch_bounds__(256) void k_pww(const float* __restrict__ z,
                                             const float* __restrict__ pa_w,
                                             const float* __restrict__ pb_w,
                                             const float* __restrict__ pc_w,
                                             const float* __restrict__ pd_w,
                                             unsigned short* __restrict__ wse) {
    int i = blockIdx.x * 256 + threadIdx.x;
    if (i >= NB * NC * NC) return;
    int b = i / (NC * NC), rem = i % (NC * NC);
    int o = rem / NC, c = rem % NC;
    int br = o / NBC, lc = o % NBC;
    const float* P = (br == 0) ? pa_w : (br == 1) ? pb_w : (br == 2) ? pc_w : pd_w;
    wse[i] = f2bf(P[lc * NC + c] * z[b * NC + c]);
}

// ---- K4: MFMA pointwise. Conv channels (0..47) -> ut48[b][n][48] (transposed
//      via LDS bounce); pool/identity channels (48..95) -> u2[b][ch][n]. ----
__global__ __launch_bounds__(256) void k_pwg(const unsigned short* __restrict__ x3,
                                             const unsigned short* __restrict__ wse,
                                             const float* __restrict__ pa_bn,
                                             const float* __restrict__ pb_bn,
                                             const float* __restrict__ pc_bn,
                                             const float* __restrict__ pd_bn,
                                             unsigned short* __restrict__ ut48,
                                             unsigned short* __restrict__ u2) {
    int blk = blockIdx.x;
    int b = blk / 50;
    int n0 = (blk % 50) * 128;
    int tid = threadIdx.x;
    __shared__ __align__(16) char SMEM[33280];
    unsigned short* Wpan = (unsigned short*)SMEM;
    unsigned short* Xp = Wpan + 3 * NC * APAD;
    float* Yt = (float*)SMEM;

    int lane = tid & 63, wv = tid >> 6;
    int lr = lane & 15, kg = lane >> 4;
    f32x4 acc[6][2];
#pragma unroll
    for (int mt = 0; mt < 6; ++mt)
#pragma unroll
        for (int nn = 0; nn < 2; ++nn) acc[mt][nn] = (f32x4){0.f, 0.f, 0.f, 0.f};

    const unsigned short* wb = wse + (size_t)b * NC * NC;
    for (int i = tid; i < 3 * NC * 4; i += 256) {
        int kt = i / (NC * 4), rem = i % (NC * 4);
        int o = rem >> 2, s4 = rem & 3;
        *(bf16x8*)&Wpan[(kt * NC + o) * APAD + s4 * 8] =
            *(const bf16x8*)(wb + o * NC + kt * 32 + s4 * 8);
    }

    int kp = tid >> 4;
    int seg = tid & 15;
    const unsigned short* x3b = x3 + (size_t)b * NC * NN;

    for (int kt = 0; kt < 3; ++kt) {
        int k0 = kt * 32;
        {
            const unsigned short* src0 = x3b + (size_t)(k0 + 2 * kp) * NN + n0 + seg * 8;
            bf16x8 va = *(const bf16x8*)src0;
            bf16x8 vb = *(const bf16x8*)(src0 + NN);
            char* base = (char*)Xp;
#pragma unroll
            for (int e = 0; e < 8; ++e) {
                int n = seg * 8 + e;
                int g = (kp >> 2) ^ (n & 3) ^ ((n >> 3) & 3);
                unsigned pk = (unsigned)(unsigned short)va[e] |
                              ((unsigned)(unsigned short)vb[e] << 16);
                *(unsigned*)(base + n * 80 + g * 16 + (kp & 3) * 4) = pk;
            }
        }
        __syncthreads();
        bf16x8 afr[6];
#pragma unroll
        for (int mt = 0; mt < 6; ++mt)
            afr[mt] = *(const bf16x8*)&Wpan[(kt * NC + mt * 16 + lr) * APAD + kg * 8];
#pragma unroll
        for (int nn = 0; nn < 2; ++nn) {
            int nl = (wv * 2 + nn) * 16 + lr;
            int g = kg ^ (nl & 3) ^ ((nl >> 3) & 3);
            bf16x8 bb = *(const bf16x8*)((const char*)Xp + nl * 80 + g * 16);
#pragma unroll
            for (int mt = 0; mt < 6; ++mt)
                acc[mt][nn] = __builtin_amdgcn_mfma_f32_16x16x32_bf16(afr[mt], bb, acc[mt][nn], 0, 0, 0);
        }
        __syncthreads();
    }
#pragma unroll
    for (int mt = 0; mt < 6; ++mt)
#pragma unroll
        for (int nn = 0; nn < 2; ++nn) {
            int nl = (wv * 2 + nn) * 16 + lr;
#pragma unroll
            for (int i = 0; i < 4; ++i) {
                int o = mt * 16 + kg * 4 + i;
                int br = o / NBC, lc = o % NBC;
                const float* bnp = (br == 0) ? pa_bn : (br == 1) ? pb_bn
                                 : (br == 2) ? pc_bn : pd_bn;
                float val = bnval(acc[mt][nn][i], bnp, NBC, lc);
                if (br < 2) {
                    Yt[nl * 49 + o] = hswish(val);
                } else {
                    u2[((size_t)b * 48 + (o - 48)) * NN + n0 + nl] = f2bf(val);
                }
            }
        }
    __syncthreads();
    for (int i = tid; i < 128 * 6; i += 256) {
        int n = i / 6, og = i % 6;
        bf16x8 v;
#pragma unroll
        for (int e = 0; e < 8; ++e) v[e] = (short)f2bf(Yt[n * 49 + og * 8 + e]);
        *(bf16x8*)(ut48 + ((size_t)b * NN + n0 + n) * 48 + og * 8) = v;
    }
}

// ---- K5: MFMA temporal convs -> uc[b][oc][n] = bn(conv) (bf16, no residual) ----
__global__ __launch_bounds__(256) void k_tcnm(const unsigned short* __restrict__ ut48,
                                              const unsigned short* __restrict__ wtw,
                                              const float* __restrict__ ta_bn,
                                              const float* __restrict__ tb_bn,
                                              unsigned short* __restrict__ uc) {
    int blk = blockIdx.x;
    int b = blk / 50, n0 = (blk % 50) * 128;
    int tid = threadIdx.x;
    __shared__ __align__(16) unsigned short Ut[240][56];
    int wn = n0 - 56;
    const unsigned short* utb = ut48 + (size_t)b * NN * 48;
    for (int idx = tid; idx < 240 * 6; idx += 256) {
        int row = idx / 6, seg = idx % 6;
        int n = wn + row;
        bf16x8 val = {0, 0, 0, 0, 0, 0, 0, 0};
        if (n >= 0 && n < NN)
            val = *(const bf16x8*)(utb + (size_t)n * 48 + seg * 8);
        *(bf16x8*)&Ut[row][seg * 8] = val;
    }
    int lane = tid & 63, wave = tid >> 6;
    int lr = lane & 15, kg = lane >> 4;
    int br = wave >> 1, mh = wave & 1;
    int dn = 25 + br * 25;
    bf16x8 af[3];
#pragma unroll
    for (int kt = 0; kt < 3; ++kt)
        af[kt] = *(const bf16x8*)(wtw + (br * 32 + mh * 16 + lr) * 96 + kt * 32 + kg * 8);
    __syncthreads();

    f32x4 acc[8];
#pragma unroll
    for (int nt = 0; nt < 8; ++nt) acc[nt] = (f32x4){0.f, 0.f, 0.f, 0.f};
#pragma unroll
    for (int kt = 0; kt < 3; ++kt) {
        int g = kt * 4 + kg;
        int gg = (g > 8) ? 8 : g;
        int i3 = gg / 3;
        int c2b = (gg - i3 * 3) * 8;
        int roff = 56 + (i3 - 1) * dn;
        int colb = br * 24 + c2b;
#pragma unroll
        for (int nt = 0; nt < 8; ++nt) {
            int nrow = nt * 16 + lr + roff;
            bf16x8 bb = *(const bf16x8*)&Ut[nrow][colb];
            acc[nt] = __builtin_amdgcn_mfma_f32_16x16x32_bf16(af[kt], bb, acc[nt], 0, 0, 0);
        }
    }
    const float* bnp = br ? tb_bn : ta_bn;
    int ml = mh * 16 + kg * 4;
#pragma unroll
    for (int ii = 0; ii < 4; ++ii) {
        int ol = ml + ii;
        if (ol < 24) {
            int oc = br * 24 + ol;
#pragma unroll
            for (int nt = 0; nt < 8; ++nt) {
                int n = n0 + nt * 16 + lr;
                uc[((size_t)b * 48 + oc) * NN + n] = f2bf(bnval(acc[nt][ii], bnp, NBC, ol));
            }
        }
    }
}

// ---- K6: streaming finale: out = hswish(branch_val + x) for all 96 channels ----
__global__ __launch_bounds__(256) void k_fin(const unsigned short* __restrict__ uc,
                                             const unsigned short* __restrict__ u2,
                                             const float* __restrict__ x,
                                             float* __restrict__ out) {
    const int JV = NN / 8;
    const int NVEC = NB * NC * JV;
    for (int vid = blockIdx.x * 256 + threadIdx.x; vid < NVEC; vid += gridDim.x * 256) {
        int j = vid % JV;
        int bc = vid / JV;
        int ch = bc % NC, b = bc / NC;
        int n = j * 8;
        float val[8];
        if (ch < 48) {
            bf16x8 t = *(const bf16x8*)(uc + ((size_t)b * 48 + ch) * NN + n);
#pragma unroll
            for (int e = 0; e < 8; ++e) val[e] = bf2f((unsigned short)t[e]);
        } else if (ch < 72) {
            const unsigned short* p = u2 + ((size_t)b * 48 + (ch - 48)) * NN;
            if (j >= 4 && j <= JV - 5) {
                bf16x8 M = *(const bf16x8*)(p + n);
                bf16x8 Lm = *(const bf16x8*)(p + n - 24);
                bf16x8 Rp = *(const bf16x8*)(p + n + 24);
                float lm1 = bf2f(p[n - 25]);
                float rp1 = bf2f(p[n + 32]);
#pragma unroll
                for (int e = 0; e < 8; ++e) {
                    float vm = (e == 0) ? lm1 : bf2f((unsigned short)Lm[e - 1]);
                    float vp = (e == 7) ? rp1 : bf2f((unsigned short)Rp[e + 1]);
                    val[e] = fmaxf(fmaxf(bf2f((unsigned short)M[e]), vm), vp);
                }
            } else {
#pragma unroll
                for (int e = 0; e < 8; ++e) {
                    int ne = n + e;
                    float m = bf2f(p[ne]);
                    if (ne >= 25) m = fmaxf(m, bf2f(p[ne - 25]));
                    if (ne + 25 < NN) m = fmaxf(m, bf2f(p[ne + 25]));
                    val[e] = m;
                }
            }
        } else {
            bf16x8 t = *(const bf16x8*)(u2 + ((size_t)b * 48 + (ch - 48)) * NN + n);
#pragma unroll
            for (int e = 0; e < 8; ++e) val[e] = bf2f((unsigned short)t[e]);
        }
        const float* xp = x + (size_t)bc * NN + n;
        float* op = out + (size_t)bc * NN + n;
        f32x4 x0 = *(const f32x4*)xp;
        f32x4 x1 = *(const f32x4*)(xp + 4);
        f32x4 o0, o1;
#pragma unroll
        for (int e = 0; e < 4; ++e) o0[e] = hswish(val[e] + x0[e]);
#pragma unroll
        for (int e = 0; e < 4; ++e) o1[e] = hswish(val[e + 4] + x1[e]);
        *(f32x4*)op = o0;
        *(f32x4*)(op + 4) = o1;
    }
}

extern "C" void kernel_launch(void* const* d_in, const int* in_sizes, int n_in,
                              void* d_out, int out_size, void* d_ws, size_t ws_size,
                              hipStream_t stream) {
    const float* x = (const float*)d_in[0];
    const int* intra = (const int*)d_in[1];
    const int* inter = (const int*)d_in[2];
    const float* A_gcn = (const float*)d_in[3];
    const float* W_gcn = (const float*)d_in[4];
    const float* gcn_bn = (const float*)d_in[5];
    const float* Wp = (const float*)d_in[6];
    const float* W_adyn = (const float*)d_in[7];
    const float* gate = (const float*)d_in[8];
    const float* se_w1 = (const float*)d_in[9];
    const float* se_b1 = (const float*)d_in[10];
    const float* se_w2 = (const float*)d_in[11];
    const float* se_b2 = (const float*)d_in[12];
    const float* pa_w = (const float*)d_in[13];
    const float* pa_bn = (const float*)d_in[14];
    const float* ta_w = (const float*)d_in[15];
    const float* ta_bn = (const float*)d_in[16];
    const float* pb_w = (const float*)d_in[17];
    const float* pb_bn = (const float*)d_in[18];
    const float* tb_w = (const float*)d_in[19];
    const float* tb_bn = (const float*)d_in[20];
    const float* pc_w = (const float*)d_in[21];
    const float* pc_bn = (const float*)d_in[22];
    const float* pd_w = (const float*)d_in[23];
    const float* pd_bn = (const float*)d_in[24];
    float* out = (float*)d_out;

    // workspace layout (bytes, every slice 16B-aligned)
    char* wsb = (char*)d_ws;
    const size_t ELEMS = (size_t)NB * NC * NT * NV;        // 19,660,800
    const size_t HALF = (size_t)NB * NN * 48;              // 9,830,400
    const size_t XSH = (size_t)NB * NC * NT * 32;          // 25,165,824
    unsigned short* x3 = (unsigned short*)wsb;                       // 2*ELEMS B
    unsigned short* ut48 = x3 + ELEMS;                               // 2*HALF B ([b][n][48])
    unsigned short* u2 = ut48 + HALF;                                // 2*HALF B ([b][ch][n])
    unsigned short* uc = u2 + HALF;                                  // 2*HALF B ([b][oc][n])
    unsigned short* xsh = uc + HALF;                                 // 2*XSH B  ([b,c,t][32])
    float* xm = (float*)(xsh + XSH);                                 // 307,200 B
    float* sb = xm + NB * NC * NV;                                   // 12,288 B
    float* zb = sb + NB * NC;                                        // 12,288 B
    unsigned short* wcat = (unsigned short*)(zb + NB * NC);          // 73,728 B
    unsigned short* acat = wcat + NC * NK4;                          // 286,720 B
    unsigned short* wse = acat + NB * ACOLS * APAD;                  // 589,824 B
    unsigned short* wtw = wse + (size_t)NB * NC * NC;                // 12,288 B

    k_mean<<<NB * NC, 256, 0, stream>>>(x, intra, inter, xm, xsh);
    k_adyn<<<NB, 256, 0, stream>>>(xm, Wp, intra, inter, A_gcn, gate, acat);
    k_wcat<<<(NC * NK4 + 255) / 256, 256, 0, stream>>>(W_gcn, W_adyn, wcat);
    k_twp<<<(2 * 32 * 96 + 255) / 256, 256, 0, stream>>>(ta_w, tb_w, wtw);
    k_gcn2<<<NB * 32, 256, 0, stream>>>(xsh, acat, wcat, gcn_bn, x3);
    k_sred<<<NB * NC, 256, 0, stream>>>(x3, sb);
    k_se<<<NB, 128, 0, stream>>>(sb, se_w1, se_b1, se_w2, se_b2, zb);
    k_pww<<<(NB * NC * NC + 255) / 256, 256, 0, stream>>>(zb, pa_w, pb_w, pc_w, pd_w, wse);
    k_pwg<<<NB * 50, 256, 0, stream>>>(x3, wse, pa_bn, pb_bn, pc_bn, pd_bn, ut48, u2);
    k_tcnm<<<NB * 50, 256, 0, stream>>>(ut48, wtw, ta_bn, tb_bn, uc);
    k_fin<<<2048, 256, 0, stream>>>(uc, u2, x, out);
}